// Round 1
// baseline (171.121 us; speedup 1.0000x reference)
//
#include <hip/hip_runtime.h>
#include <hip/hip_bf16.h>
#include <math.h>

typedef __bf16 bf16;
typedef __attribute__((ext_vector_type(8))) __bf16 bf16x8;
typedef __attribute__((ext_vector_type(4))) __bf16 bf16x4;
typedef __attribute__((ext_vector_type(4))) float f32x4;

#define MFMA(a,b,c) __builtin_amdgcn_mfma_f32_16x16x32_bf16(a,b,c,0,0,0)

static constexpr int Bb = 4, Nn = 2048, Hh = 4;
static constexpr int Mrows = Bb * Nn;                // 8192 rows per sequence
static constexpr float SS = 0.35355339059327373f;    // SCALE^0.5 = 8^-0.5

// ---------------- weight prep: f32 [K][N] -> bf16 [N][K] ----------------
__global__ __launch_bounds__(256) void prep_weights(
    const float* Wqk, const float* Wv, const float* Wout,
    const float* Wf1, const float* Wf2,
    bf16* wqk_t, bf16* wv_t, bf16* wout_t, bf16* wf1_t, bf16* wf2_t) {
  int id = blockIdx.x * 256 + threadIdx.x;
  if (id < 65536) { int k = id >> 8, n = id & 255; wqk_t[n*256 + k] = (bf16)Wqk[id]; return; }
  id -= 65536;
  if (id < 65536) { int k = id >> 8, n = id & 255; wv_t[n*256 + k] = (bf16)Wv[id]; return; }
  id -= 65536;
  if (id < 65536) { int k = id >> 8, n = id & 255; wout_t[n*256 + k] = (bf16)Wout[id]; return; }
  id -= 65536;
  if (id < 262144) { int k = id >> 9, n = id & 511; wf1_t[n*512 + k] = (bf16)Wf1[id]; return; }
  id -= 262144;
  if (id < 131072) { int k = id >> 8, n = id & 255; wf2_t[n*512 + k] = (bf16)Wf2[id]; return; }
}

// ---------------- generic MFMA GEMM, 128x64 tile, BK=64 ----------------
// MODE 0: A=x f32, out = (acc+bqk)*SS -> qks bf16 [B,H,N,64]
// MODE 1: A=x f32, out = acc+bv       -> vT  bf16 [B,H,64,N]
// MODE 2: A=m bf16, out = acc+bout    -> mo  bf16 [8192,256]
// MODE 3: A=concat(x f32, mo bf16), out = acc+bf1 -> h f32 [8192,512]
// MODE 4: A=hg bf16, out = acc+bf2+x  -> y f32 [8192,256]
template<int MODE>
__global__ __launch_bounds__(256) void gemm_k(
    const float* Af0, const float* Af1,
    const bf16* Ab0, const bf16* Ab1,
    const bf16* Wt, const float* bias,
    bf16* ob0, bf16* ob1, float* of0, float* of1,
    const float* res0, const float* res1,
    int Kdim) {
  const int z = blockIdx.z;
  const float* Af = z ? Af1 : Af0;
  const bf16*  Ab = z ? Ab1 : Ab0;
  bf16*  ob = z ? ob1 : ob0;
  float* of = z ? of1 : of0;
  const float* res = z ? res1 : res0;

  const int tid = threadIdx.x;
  const int lane = tid & 63;
  const int w = tid >> 6;
  const int wr = w >> 1, wc = w & 1;
  const int m0r = blockIdx.x * 128;
  const int n0 = blockIdx.y * 64;

  __shared__ bf16 At[128][72];   // 144B rows: 16B-aligned, 2-way banks
  __shared__ bf16 Bt[64][72];

  f32x4 acc[4][2];
#pragma unroll
  for (int i = 0; i < 4; i++)
#pragma unroll
    for (int j = 0; j < 2; j++) acc[i][j] = f32x4{0.f, 0.f, 0.f, 0.f};

  const int nkc = Kdim >> 6;
  for (int kc = 0; kc < nkc; ++kc) {
    const int k0 = kc * 64;
    // ---- stage A tile (128 x 64) as bf16 ----
    if (MODE == 0 || MODE == 1 || (MODE == 3 && kc < 4)) {
      const int lda = (MODE == 3) ? 256 : Kdim;
#pragma unroll
      for (int i = 0; i < 8; i++) {
        int idx = i * 256 + tid;
        int row = idx >> 4, c4 = (idx & 15) * 4;
        f32x4 v = *reinterpret_cast<const f32x4*>(&Af[(size_t)(m0r + row) * lda + k0 + c4]);
        bf16x4 o; o[0] = (bf16)v[0]; o[1] = (bf16)v[1]; o[2] = (bf16)v[2]; o[3] = (bf16)v[3];
        *reinterpret_cast<bf16x4*>(&At[row][c4]) = o;
      }
    } else {
      const int lda = (MODE == 3) ? 256 : ((MODE == 4) ? 512 : 256);
      const int kk0 = (MODE == 3) ? (k0 - 256) : k0;
#pragma unroll
      for (int i = 0; i < 4; i++) {
        int idx = i * 256 + tid;
        int row = idx >> 3, c8 = (idx & 7) * 8;
        *reinterpret_cast<uint4*>(&At[row][c8]) =
            *reinterpret_cast<const uint4*>(&Ab[(size_t)(m0r + row) * lda + kk0 + c8]);
      }
    }
    // ---- stage B tile from Wt bf16 [N][K] ----
#pragma unroll
    for (int i = 0; i < 2; i++) {
      int idx = i * 256 + tid;
      int row = idx >> 3, c8 = (idx & 7) * 8;
      *reinterpret_cast<uint4*>(&Bt[row][c8]) =
          *reinterpret_cast<const uint4*>(&Wt[(size_t)(n0 + row) * Kdim + k0 + c8]);
    }
    __syncthreads();
    // ---- compute ----
#pragma unroll
    for (int ks = 0; ks < 2; ++ks) {
      bf16x8 af[4], bfr[2];
#pragma unroll
      for (int mf = 0; mf < 4; ++mf)
        af[mf] = *reinterpret_cast<const bf16x8*>(&At[wr*64 + mf*16 + (lane & 15)][ks*32 + (lane >> 4) * 8]);
#pragma unroll
      for (int nf = 0; nf < 2; ++nf)
        bfr[nf] = *reinterpret_cast<const bf16x8*>(&Bt[wc*32 + nf*16 + (lane & 15)][ks*32 + (lane >> 4) * 8]);
#pragma unroll
      for (int mf = 0; mf < 4; ++mf)
#pragma unroll
        for (int nf = 0; nf < 2; ++nf)
          acc[mf][nf] = MFMA(af[mf], bfr[nf], acc[mf][nf]);
    }
    __syncthreads();
  }

  // ---- epilogue ----
#pragma unroll
  for (int mf = 0; mf < 4; ++mf)
#pragma unroll
    for (int nf = 0; nf < 2; ++nf) {
      f32x4 c = acc[mf][nf];
      int cg = n0 + wc*32 + nf*16 + (lane & 15);
      float bv = bias[cg];
#pragma unroll
      for (int r = 0; r < 4; ++r) {
        int rg = m0r + wr*64 + mf*16 + (lane >> 4) * 4 + r;
        float val = c[r] + bv;
        if constexpr (MODE == 0) {
          val *= SS;
          int b = rg >> 11, n = rg & 2047, h = cg >> 6, dh = cg & 63;
          ob[(((size_t)(b*Hh + h)) * Nn + n) * 64 + dh] = (bf16)val;
        } else if constexpr (MODE == 1) {
          int b = rg >> 11, n = rg & 2047, h = cg >> 6, dh = cg & 63;
          ob[(((size_t)(b*Hh + h)) * 64 + dh) * Nn + n] = (bf16)val;
        } else if constexpr (MODE == 2) {
          ob[(size_t)rg * 256 + cg] = (bf16)val;
        } else if constexpr (MODE == 3) {
          of[(size_t)rg * 512 + cg] = val;
        } else {
          of[(size_t)rg * 256 + cg] = val + res[(size_t)rg * 256 + cg];
        }
      }
    }
}

// ---------------- fused dual-direction attention ----------------
// grid: (32 i-tiles, 16 bh, 2 dir). exp(S)/rowsum softmax (no max needed:
// |S| <= ~16 by construction).
__global__ __launch_bounds__(256) void attn_k(
    const bf16* qks0, const bf16* qks1, const bf16* vT0, const bf16* vT1,
    bf16* m0o, bf16* m1o) {
  const int dir = blockIdx.z;
  const int bh = blockIdx.y;
  const int it = blockIdx.x;
  const bf16* Q  = (dir ? qks1 : qks0) + (size_t)bh * Nn * 64;
  const bf16* Kp = (dir ? qks0 : qks1) + (size_t)bh * Nn * 64;
  const bf16* Vp = (dir ? vT0 : vT1) + (size_t)bh * 64 * Nn;
  bf16* out = dir ? m1o : m0o;
  const int b = bh >> 2, h = bh & 3;

  const int tid = threadIdx.x, lane = tid & 63, w = tid >> 6;
  const int i0 = it * 64;
  const int riw = w * 16;

  __shared__ bf16 Kt[64][72];
  __shared__ bf16 Vt[64][72];      // Vt[d][j]
  __shared__ bf16 Eb[4][16][72];   // per-wave P re-layout buffer

  bf16x8 qf[2];
#pragma unroll
  for (int ks = 0; ks < 2; ++ks)
    qf[ks] = *reinterpret_cast<const bf16x8*>(
        &Q[(size_t)(i0 + riw + (lane & 15)) * 64 + ks*32 + (lane >> 4) * 8]);

  f32x4 acc[4];
#pragma unroll
  for (int i = 0; i < 4; i++) acc[i] = f32x4{0.f, 0.f, 0.f, 0.f};
  float rp[4] = {0.f, 0.f, 0.f, 0.f};

  for (int jt = 0; jt < 32; ++jt) {
    const int j0 = jt * 64;
#pragma unroll
    for (int i = 0; i < 2; i++) {
      int idx = i * 256 + tid;
      int row = idx >> 3, c8 = (idx & 7) * 8;
      *reinterpret_cast<uint4*>(&Kt[row][c8]) =
          *reinterpret_cast<const uint4*>(&Kp[(size_t)(j0 + row) * 64 + c8]);
      *reinterpret_cast<uint4*>(&Vt[row][c8]) =
          *reinterpret_cast<const uint4*>(&Vp[(size_t)row * Nn + j0 + c8]);
    }
    __syncthreads();

    f32x4 s[4];
#pragma unroll
    for (int js = 0; js < 4; ++js) {
      bf16x8 k0f = *reinterpret_cast<const bf16x8*>(&Kt[js*16 + (lane & 15)][(lane >> 4) * 8]);
      bf16x8 k1f = *reinterpret_cast<const bf16x8*>(&Kt[js*16 + (lane & 15)][32 + (lane >> 4) * 8]);
      f32x4 t{0.f, 0.f, 0.f, 0.f};
      t = MFMA(qf[0], k0f, t);
      t = MFMA(qf[1], k1f, t);
      s[js] = t;
    }
#pragma unroll
    for (int js = 0; js < 4; ++js)
#pragma unroll
      for (int r = 0; r < 4; ++r) {
        float e = __expf(s[js][r]);
        rp[r] += e;
        Eb[w][(lane >> 4) * 4 + r][js*16 + (lane & 15)] = (bf16)e;
      }
    bf16x8 ef[2];
#pragma unroll
    for (int ks = 0; ks < 2; ++ks)
      ef[ks] = *reinterpret_cast<const bf16x8*>(&Eb[w][lane & 15][ks*32 + (lane >> 4) * 8]);
#pragma unroll
    for (int ds = 0; ds < 4; ++ds)
#pragma unroll
      for (int ks = 0; ks < 2; ++ks) {
        bf16x8 vf = *reinterpret_cast<const bf16x8*>(&Vt[ds*16 + (lane & 15)][ks*32 + (lane >> 4) * 8]);
        acc[ds] = MFMA(ef[ks], vf, acc[ds]);
      }
    __syncthreads();
  }

#pragma unroll
  for (int r = 0; r < 4; r++) {
    rp[r] += __shfl_xor(rp[r], 1);
    rp[r] += __shfl_xor(rp[r], 2);
    rp[r] += __shfl_xor(rp[r], 4);
    rp[r] += __shfl_xor(rp[r], 8);
  }
#pragma unroll
  for (int ds = 0; ds < 4; ++ds)
#pragma unroll
    for (int r = 0; r < 4; ++r) {
      int row = i0 + riw + (lane >> 4) * 4 + r;
      int col = h * 64 + ds*16 + (lane & 15);
      out[((size_t)b * Nn + row) * 256 + col] = (bf16)(acc[ds][r] / rp[r]);
    }
}

// ---------------- LayerNorm + exact GELU, one 512-col row per block ----------------
__global__ __launch_bounds__(256) void ln_gelu_k(
    const float* hbuf, const float* g, const float* bb, bf16* hg) {
  const size_t row = blockIdx.x + (size_t)blockIdx.z * Mrows;
  const int tid = threadIdx.x;
  const float* hr = hbuf + row * 512;
  float2 v = *reinterpret_cast<const float2*>(&hr[tid * 2]);
  float s = v.x + v.y;
  float sq = v.x * v.x + v.y * v.y;
#pragma unroll
  for (int m = 1; m < 64; m <<= 1) {
    s += __shfl_xor(s, m);
    sq += __shfl_xor(sq, m);
  }
  __shared__ float ws_s[4], ws_q[4];
  int w = tid >> 6, lane = tid & 63;
  if (lane == 0) { ws_s[w] = s; ws_q[w] = sq; }
  __syncthreads();
  s = ws_s[0] + ws_s[1] + ws_s[2] + ws_s[3];
  sq = ws_q[0] + ws_q[1] + ws_q[2] + ws_q[3];
  float mu = s * (1.f / 512.f);
  float var = sq * (1.f / 512.f) - mu * mu;
  float rs = rsqrtf(var + 1e-5f);
  bf16* og = hg + row * 512;
#pragma unroll
  for (int i = 0; i < 2; i++) {
    int c = tid * 2 + i;
    float xv = i ? v.y : v.x;
    float xn = (xv - mu) * rs * g[c] + bb[c];
    float ge = 0.5f * xn * (1.f + erff(xn * 0.70710678118f));
    og[c] = (bf16)ge;
  }
}

extern "C" void kernel_launch(void* const* d_in, const int* in_sizes, int n_in,
                              void* d_out, int out_size, void* d_ws, size_t ws_size,
                              hipStream_t stream) {
  (void)in_sizes; (void)n_in; (void)out_size; (void)ws_size;
  const float* x0   = (const float*)d_in[0];
  const float* x1   = (const float*)d_in[1];
  const float* Wqk  = (const float*)d_in[2];
  const float* bqk  = (const float*)d_in[3];
  const float* Wv   = (const float*)d_in[4];
  const float* bv   = (const float*)d_in[5];
  const float* Wout = (const float*)d_in[6];
  const float* bout = (const float*)d_in[7];
  const float* Wf1  = (const float*)d_in[8];
  const float* bf1  = (const float*)d_in[9];
  const float* ln_g = (const float*)d_in[10];
  const float* ln_b = (const float*)d_in[11];
  const float* Wf2  = (const float*)d_in[12];
  const float* bf2  = (const float*)d_in[13];
  float* y = (float*)d_out;

  bf16* p = (bf16*)d_ws;
  bf16* wqk_t  = p; p += 65536;
  bf16* wv_t   = p; p += 65536;
  bf16* wout_t = p; p += 65536;
  bf16* wf1_t  = p; p += 262144;
  bf16* wf2_t  = p; p += 131072;
  bf16* qks0 = p; p += 2097152;
  bf16* qks1 = p; p += 2097152;
  bf16* vT0  = p; p += 2097152;
  bf16* vT1  = p; p += 2097152;
  bf16* m0   = p; p += 2097152;
  bf16* m1   = p; p += 2097152;
  bf16* mo0  = p; p += 2097152;
  bf16* mo1  = p; p += 2097152;
  bf16* hg0  = p; p += 4194304;
  bf16* hg1  = p; p += 4194304;
  float* hb = (float*)(((uintptr_t)p + 255) & ~(uintptr_t)255);
  float* hb0 = hb;
  float* hb1 = hb + 4194304;

  dim3 blk(256);
  prep_weights<<<2304, blk, 0, stream>>>(Wqk, Wv, Wout, Wf1, Wf2,
                                         wqk_t, wv_t, wout_t, wf1_t, wf2_t);
  gemm_k<0><<<dim3(64, 4, 2), blk, 0, stream>>>(x0, x1, nullptr, nullptr, wqk_t, bqk,
                                                qks0, qks1, nullptr, nullptr, nullptr, nullptr, 256);
  gemm_k<1><<<dim3(64, 4, 2), blk, 0, stream>>>(x0, x1, nullptr, nullptr, wv_t, bv,
                                                vT0, vT1, nullptr, nullptr, nullptr, nullptr, 256);
  attn_k<<<dim3(32, 16, 2), blk, 0, stream>>>(qks0, qks1, vT0, vT1, m0, m1);
  gemm_k<2><<<dim3(64, 4, 2), blk, 0, stream>>>(nullptr, nullptr, m0, m1, wout_t, bout,
                                                mo0, mo1, nullptr, nullptr, nullptr, nullptr, 256);
  gemm_k<3><<<dim3(64, 8, 2), blk, 0, stream>>>(x0, x1, mo0, mo1, wf1_t, bf1,
                                                nullptr, nullptr, hb0, hb1, nullptr, nullptr, 512);
  ln_gelu_k<<<dim3(8192, 1, 2), blk, 0, stream>>>(hb, ln_g, ln_b, hg0);
  gemm_k<4><<<dim3(64, 4, 2), blk, 0, stream>>>(nullptr, nullptr, hg0, hg1, wf2_t, bf2,
                                                nullptr, nullptr, y, y + 2097152, x0, x1, 512);
}

// Round 2
// 140.994 us; speedup vs baseline: 1.2137x; 1.2137x over previous
//
#include <hip/hip_runtime.h>
#include <hip/hip_bf16.h>
#include <math.h>

typedef __bf16 bf16;
typedef __attribute__((ext_vector_type(8))) __bf16 bf16x8;
typedef __attribute__((ext_vector_type(4))) __bf16 bf16x4;
typedef __attribute__((ext_vector_type(2))) __bf16 bf16x2;
typedef __attribute__((ext_vector_type(4))) float f32x4;

#define MFMA(a,b,c) __builtin_amdgcn_mfma_f32_16x16x32_bf16(a,b,c,0,0,0)

static constexpr int Bb = 4, Nn = 2048, Hh = 4;
static constexpr int Mrows = Bb * Nn;                // 8192 rows per sequence
static constexpr float SS = 0.35355339059327373f;    // SCALE^0.5 = 8^-0.5

__device__ __forceinline__ void lds16(const bf16* src, bf16* dst) {
  __builtin_amdgcn_global_load_lds(
      (const __attribute__((address_space(1))) void*)src,
      (__attribute__((address_space(3))) void*)dst, 16, 0, 0);
}

// ---------------- weight prep: f32 [K][N] -> bf16 [N][K] ----------------
__global__ __launch_bounds__(256) void prep_weights(
    const float* Wqk, const float* Wv, const float* Wout,
    const float* Wf1, const float* Wf2,
    bf16* wqk_t, bf16* wv_t, bf16* wout_t, bf16* wf1_t, bf16* wf2_t) {
  int id = blockIdx.x * 256 + threadIdx.x;
  if (id < 65536) { int k = id >> 8, n = id & 255; wqk_t[n*256 + k] = (bf16)Wqk[id]; return; }
  id -= 65536;
  if (id < 65536) { int k = id >> 8, n = id & 255; wv_t[n*256 + k] = (bf16)Wv[id]; return; }
  id -= 65536;
  if (id < 65536) { int k = id >> 8, n = id & 255; wout_t[n*256 + k] = (bf16)Wout[id]; return; }
  id -= 65536;
  if (id < 262144) { int k = id >> 9, n = id & 511; wf1_t[n*512 + k] = (bf16)Wf1[id]; return; }
  id -= 262144;
  if (id < 131072) { int k = id >> 8, n = id & 255; wf2_t[n*512 + k] = (bf16)Wf2[id]; return; }
}

// ---------------- generic MFMA GEMM, 128x64 tile, BK=64 (unchanged) ----------------
template<int MODE>
__global__ __launch_bounds__(256) void gemm_k(
    const float* Af0, const float* Af1,
    const bf16* Ab0, const bf16* Ab1,
    const bf16* Wt, const float* bias,
    bf16* ob0, bf16* ob1, float* of0, float* of1,
    const float* res0, const float* res1,
    int Kdim) {
  const int z = blockIdx.z;
  const float* Af = z ? Af1 : Af0;
  const bf16*  Ab = z ? Ab1 : Ab0;
  bf16*  ob = z ? ob1 : ob0;
  float* of = z ? of1 : of0;
  const float* res = z ? res1 : res0;

  const int tid = threadIdx.x;
  const int lane = tid & 63;
  const int w = tid >> 6;
  const int wr = w >> 1, wc = w & 1;
  const int m0r = blockIdx.x * 128;
  const int n0 = blockIdx.y * 64;

  __shared__ bf16 At[128][72];
  __shared__ bf16 Bt[64][72];

  f32x4 acc[4][2];
#pragma unroll
  for (int i = 0; i < 4; i++)
#pragma unroll
    for (int j = 0; j < 2; j++) acc[i][j] = f32x4{0.f, 0.f, 0.f, 0.f};

  const int nkc = Kdim >> 6;
  for (int kc = 0; kc < nkc; ++kc) {
    const int k0 = kc * 64;
    if (MODE == 0 || MODE == 1 || (MODE == 3 && kc < 4)) {
      const int lda = (MODE == 3) ? 256 : Kdim;
#pragma unroll
      for (int i = 0; i < 8; i++) {
        int idx = i * 256 + tid;
        int row = idx >> 4, c4 = (idx & 15) * 4;
        f32x4 v = *reinterpret_cast<const f32x4*>(&Af[(size_t)(m0r + row) * lda + k0 + c4]);
        bf16x4 o; o[0] = (bf16)v[0]; o[1] = (bf16)v[1]; o[2] = (bf16)v[2]; o[3] = (bf16)v[3];
        *reinterpret_cast<bf16x4*>(&At[row][c4]) = o;
      }
    } else {
      const int lda = (MODE == 3) ? 256 : ((MODE == 4) ? 512 : 256);
      const int kk0 = (MODE == 3) ? (k0 - 256) : k0;
#pragma unroll
      for (int i = 0; i < 4; i++) {
        int idx = i * 256 + tid;
        int row = idx >> 3, c8 = (idx & 7) * 8;
        *reinterpret_cast<uint4*>(&At[row][c8]) =
            *reinterpret_cast<const uint4*>(&Ab[(size_t)(m0r + row) * lda + kk0 + c8]);
      }
    }
#pragma unroll
    for (int i = 0; i < 2; i++) {
      int idx = i * 256 + tid;
      int row = idx >> 3, c8 = (idx & 7) * 8;
      *reinterpret_cast<uint4*>(&Bt[row][c8]) =
          *reinterpret_cast<const uint4*>(&Wt[(size_t)(n0 + row) * Kdim + k0 + c8]);
    }
    __syncthreads();
#pragma unroll
    for (int ks = 0; ks < 2; ++ks) {
      bf16x8 af[4], bfr[2];
#pragma unroll
      for (int mf = 0; mf < 4; ++mf)
        af[mf] = *reinterpret_cast<const bf16x8*>(&At[wr*64 + mf*16 + (lane & 15)][ks*32 + (lane >> 4) * 8]);
#pragma unroll
      for (int nf = 0; nf < 2; ++nf)
        bfr[nf] = *reinterpret_cast<const bf16x8*>(&Bt[wc*32 + nf*16 + (lane & 15)][ks*32 + (lane >> 4) * 8]);
#pragma unroll
      for (int mf = 0; mf < 4; ++mf)
#pragma unroll
        for (int nf = 0; nf < 2; ++nf)
          acc[mf][nf] = MFMA(af[mf], bfr[nf], acc[mf][nf]);
    }
    __syncthreads();
  }

#pragma unroll
  for (int mf = 0; mf < 4; ++mf)
#pragma unroll
    for (int nf = 0; nf < 2; ++nf) {
      f32x4 c = acc[mf][nf];
      int cg = n0 + wc*32 + nf*16 + (lane & 15);
      float bv = bias[cg];
#pragma unroll
      for (int r = 0; r < 4; ++r) {
        int rg = m0r + wr*64 + mf*16 + (lane >> 4) * 4 + r;
        float val = c[r] + bv;
        if constexpr (MODE == 0) {
          val *= SS;
          int b = rg >> 11, n = rg & 2047, h = cg >> 6, dh = cg & 63;
          ob[(((size_t)(b*Hh + h)) * Nn + n) * 64 + dh] = (bf16)val;
        } else if constexpr (MODE == 1) {
          int b = rg >> 11, n = rg & 2047, h = cg >> 6, dh = cg & 63;
          ob[(((size_t)(b*Hh + h)) * 64 + dh) * Nn + n] = (bf16)val;
        } else if constexpr (MODE == 2) {
          ob[(size_t)rg * 256 + cg] = (bf16)val;
        } else if constexpr (MODE == 3) {
          of[(size_t)rg * 512 + cg] = val;
        } else {
          of[(size_t)rg * 256 + cg] = val + res[(size_t)rg * 256 + cg];
        }
      }
    }
}

// ---------------- fused dual-direction attention, pipelined ----------------
// 128 i-rows/block (4 waves x 32), j-tile 64, double-buffered K/V via
// global_load_lds + counted vmcnt + raw barriers, XOR-swizzled LDS,
// swapped QK^T (S^T) so E packs as bf16x2, rowsum via mfma(E, ones).
__global__ __launch_bounds__(256, 2) void attn_k(
    const bf16* qks0, const bf16* qks1, const bf16* vT0, const bf16* vT1,
    bf16* m0o, bf16* m1o) {
  const int dir = blockIdx.z;
  const int bh  = blockIdx.y;
  const int it  = blockIdx.x;                 // 16 i-tiles of 128 rows
  const bf16* Q  = (dir ? qks1 : qks0) + (size_t)bh * (Nn * 64);
  const bf16* Kp = (dir ? qks0 : qks1) + (size_t)bh * (Nn * 64);
  const bf16* Vp = (dir ? vT0  : vT1 ) + (size_t)bh * (64 * Nn);
  bf16* out = dir ? m1o : m0o;
  const int b = bh >> 2, h = bh & 3;

  const int tid = threadIdx.x, lane = tid & 63, w = tid >> 6;
  const int r15 = lane & 15, g = lane >> 4, rb = r15 & 7;
  const int iw = it * 128 + w * 32;           // wave's first q-row

  __shared__ bf16 Kt[2][4096];                // [buf][64 rows x 64 cols], swizzled
  __shared__ bf16 Vt[2][4096];                // [buf][64 d    x 64 j   ], swizzled
  __shared__ bf16 Et[4][2048];                // per-wave [32 i x 64 j], swizzled

  // ---- Q fragments (registers, held entire kernel) ----
  bf16x8 qf[2][2];
#pragma unroll
  for (int f = 0; f < 2; ++f)
#pragma unroll
    for (int ks = 0; ks < 2; ++ks)
      qf[f][ks] = *reinterpret_cast<const bf16x8*>(
          &Q[(size_t)(iw + f*16 + r15) * 64 + ks*32 + g*8]);

  bf16x8 ones;
#pragma unroll
  for (int i = 0; i < 8; ++i) ones[i] = (bf16)1.0f;

  f32x4 acc[2][4];
  f32x4 rs[2];
#pragma unroll
  for (int f = 0; f < 2; ++f) {
    rs[f] = f32x4{0.f, 0.f, 0.f, 0.f};
#pragma unroll
    for (int ds = 0; ds < 4; ++ds) acc[f][ds] = f32x4{0.f, 0.f, 0.f, 0.f};
  }

  // ---- staging setup (pre-swizzled global sources, linear LDS dests) ----
  const int l3 = lane >> 3, l7 = lane & 7;
  const int swz = ((l7 ^ l3) * 8);            // element offset of 16B chunk
  const bf16* ks0 = Kp + (size_t)(w*16 +     l3) * 64 + swz;   // + j0*64
  const bf16* ks1 = Kp + (size_t)(w*16 + 8 + l3) * 64 + swz;
  const bf16* vs0 = Vp + (size_t)(w*16 +     l3) * 2048 + swz; // + j0
  const bf16* vs1 = Vp + (size_t)(w*16 + 8 + l3) * 2048 + swz;
  const int kd0 = (w*16    ) * 64;            // LDS element offsets (wave-uniform)
  const int kd1 = (w*16 + 8) * 64;

  auto stage = [&](int buf, int j0) {
    lds16(ks0 + (size_t)j0 * 64, &Kt[buf][kd0]);
    lds16(ks1 + (size_t)j0 * 64, &Kt[buf][kd1]);
    lds16(vs0 + j0,              &Vt[buf][kd0]);
    lds16(vs1 + j0,              &Vt[buf][kd1]);
  };

  // ---- read-side swizzle constants ----
  const int rx0 = ((0*4 + g) ^ rb) << 4;      // byte offset within 128B row, ks=0
  const int rx1 = ((1*4 + g) ^ rb) << 4;      // ks=1
  const int rowb = r15 << 7;                  // r15 * 128 bytes
  // E-write bases: row = f*16 + r15, chunk = (js*2 + (g>>1)) ^ rb, low = 8*(g&1)+4*rr
  const int eb0 = (r15 << 7) + ((g & 1) << 3);
  const int eb1 = eb0 + (16 << 7);
  const int gh = g >> 1;
  int cx[4];
#pragma unroll
  for (int js = 0; js < 4; ++js) cx[js] = ((js*2 + gh) ^ rb) << 4;

  char* ew = (char*)&Et[w][0];

  auto compute_tile = [&](int cur) {
    const char* Kb = (const char*)&Kt[cur][0];
    const char* Vb = (const char*)&Vt[cur][0];
    // --- QK^T (S^T fragments: rows j, cols i) ---
    f32x4 st[2][4];
    __builtin_amdgcn_s_setprio(1);
#pragma unroll
    for (int js = 0; js < 4; ++js) {
      bf16x8 k0 = *reinterpret_cast<const bf16x8*>(Kb + js*2048 + rowb + rx0);
      bf16x8 k1 = *reinterpret_cast<const bf16x8*>(Kb + js*2048 + rowb + rx1);
#pragma unroll
      for (int f = 0; f < 2; ++f) {
        f32x4 t{0.f, 0.f, 0.f, 0.f};
        t = MFMA(k0, qf[f][0], t);
        t = MFMA(k1, qf[f][1], t);
        st[f][js] = t;
      }
    }
    __builtin_amdgcn_s_setprio(0);
    // --- exp + pack pairs + swizzled E write ---
#pragma unroll
    for (int f = 0; f < 2; ++f) {
      const int ebf = f ? eb1 : eb0;
#pragma unroll
      for (int js = 0; js < 4; ++js) {
        float e0 = __expf(st[f][js][0]);
        float e1 = __expf(st[f][js][1]);
        float e2 = __expf(st[f][js][2]);
        float e3 = __expf(st[f][js][3]);
        bf16x2 p0; p0[0] = (bf16)e0; p0[1] = (bf16)e1;
        bf16x2 p1; p1[0] = (bf16)e2; p1[1] = (bf16)e3;
        *reinterpret_cast<bf16x2*>(ew + ebf + cx[js]    ) = p0;
        *reinterpret_cast<bf16x2*>(ew + ebf + cx[js] + 4) = p1;
      }
    }
    // --- PV + rowsum ---
    bf16x8 ef[2][2];
#pragma unroll
    for (int f = 0; f < 2; ++f) {
      ef[f][0] = *reinterpret_cast<const bf16x8*>(ew + f*2048 + rowb + rx0);
      ef[f][1] = *reinterpret_cast<const bf16x8*>(ew + f*2048 + rowb + rx1);
    }
    __builtin_amdgcn_s_setprio(1);
#pragma unroll
    for (int f = 0; f < 2; ++f) {
      rs[f] = MFMA(ef[f][0], ones, rs[f]);
      rs[f] = MFMA(ef[f][1], ones, rs[f]);
    }
#pragma unroll
    for (int ds = 0; ds < 4; ++ds) {
      bf16x8 v0 = *reinterpret_cast<const bf16x8*>(Vb + ds*2048 + rowb + rx0);
      bf16x8 v1 = *reinterpret_cast<const bf16x8*>(Vb + ds*2048 + rowb + rx1);
#pragma unroll
      for (int f = 0; f < 2; ++f) {
        acc[f][ds] = MFMA(ef[f][0], v0, acc[f][ds]);
        acc[f][ds] = MFMA(ef[f][1], v1, acc[f][ds]);
      }
    }
    __builtin_amdgcn_s_setprio(0);
  };

  // ---- pipelined main loop: 32 j-tiles, last one peeled ----
  stage(0, 0);
  int cur = 0;
  for (int jt = 0; jt < 31; ++jt) {
    stage(cur ^ 1, (jt + 1) << 6);
    asm volatile("s_waitcnt vmcnt(4)" ::: "memory");
    __builtin_amdgcn_sched_barrier(0);
    __builtin_amdgcn_s_barrier();
    __builtin_amdgcn_sched_barrier(0);
    compute_tile(cur);
    asm volatile("s_waitcnt lgkmcnt(0)" ::: "memory");
    __builtin_amdgcn_sched_barrier(0);
    __builtin_amdgcn_s_barrier();
    __builtin_amdgcn_sched_barrier(0);
    cur ^= 1;
  }
  asm volatile("s_waitcnt vmcnt(0)" ::: "memory");
  __builtin_amdgcn_sched_barrier(0);
  __builtin_amdgcn_s_barrier();
  __builtin_amdgcn_sched_barrier(0);
  compute_tile(cur);

  // ---- epilogue: divide by rowsum, write out ----
#pragma unroll
  for (int f = 0; f < 2; ++f) {
    f32x4 inv;
#pragma unroll
    for (int r = 0; r < 4; ++r) inv[r] = 1.0f / rs[f][r];
#pragma unroll
    for (int ds = 0; ds < 4; ++ds)
#pragma unroll
      for (int r = 0; r < 4; ++r) {
        int row = iw + f*16 + 4*g + r;
        int col = h*64 + ds*16 + r15;
        out[((size_t)b * Nn + row) * 256 + col] = (bf16)(acc[f][ds][r] * inv[r]);
      }
  }
}

// ---------------- LayerNorm + exact GELU ----------------
__global__ __launch_bounds__(256) void ln_gelu_k(
    const float* hbuf, const float* g, const float* bb, bf16* hg) {
  const size_t row = blockIdx.x + (size_t)blockIdx.z * Mrows;
  const int tid = threadIdx.x;
  const float* hr = hbuf + row * 512;
  float2 v = *reinterpret_cast<const float2*>(&hr[tid * 2]);
  float s = v.x + v.y;
  float sq = v.x * v.x + v.y * v.y;
#pragma unroll
  for (int m = 1; m < 64; m <<= 1) {
    s += __shfl_xor(s, m);
    sq += __shfl_xor(sq, m);
  }
  __shared__ float ws_s[4], ws_q[4];
  int w = tid >> 6, lane = tid & 63;
  if (lane == 0) { ws_s[w] = s; ws_q[w] = sq; }
  __syncthreads();
  s = ws_s[0] + ws_s[1] + ws_s[2] + ws_s[3];
  sq = ws_q[0] + ws_q[1] + ws_q[2] + ws_q[3];
  float mu = s * (1.f / 512.f);
  float var = sq * (1.f / 512.f) - mu * mu;
  float rs = rsqrtf(var + 1e-5f);
  bf16* og = hg + row * 512;
#pragma unroll
  for (int i = 0; i < 2; i++) {
    int c = tid * 2 + i;
    float xv = i ? v.y : v.x;
    float xn = (xv - mu) * rs * g[c] + bb[c];
    float ge = 0.5f * xn * (1.f + erff(xn * 0.70710678118f));
    og[c] = (bf16)ge;
  }
}

extern "C" void kernel_launch(void* const* d_in, const int* in_sizes, int n_in,
                              void* d_out, int out_size, void* d_ws, size_t ws_size,
                              hipStream_t stream) {
  (void)in_sizes; (void)n_in; (void)out_size; (void)ws_size;
  const float* x0   = (const float*)d_in[0];
  const float* x1   = (const float*)d_in[1];
  const float* Wqk  = (const float*)d_in[2];
  const float* bqk  = (const float*)d_in[3];
  const float* Wv   = (const float*)d_in[4];
  const float* bv   = (const float*)d_in[5];
  const float* Wout = (const float*)d_in[6];
  const float* bout = (const float*)d_in[7];
  const float* Wf1  = (const float*)d_in[8];
  const float* bf1  = (const float*)d_in[9];
  const float* ln_g = (const float*)d_in[10];
  const float* ln_b = (const float*)d_in[11];
  const float* Wf2  = (const float*)d_in[12];
  const float* bf2  = (const float*)d_in[13];
  float* y = (float*)d_out;

  bf16* p = (bf16*)d_ws;
  bf16* wqk_t  = p; p += 65536;
  bf16* wv_t   = p; p += 65536;
  bf16* wout_t = p; p += 65536;
  bf16* wf1_t  = p; p += 262144;
  bf16* wf2_t  = p; p += 131072;
  bf16* qks0 = p; p += 2097152;
  bf16* qks1 = p; p += 2097152;
  bf16* vT0  = p; p += 2097152;
  bf16* vT1  = p; p += 2097152;
  bf16* m0   = p; p += 2097152;
  bf16* m1   = p; p += 2097152;
  bf16* mo0  = p; p += 2097152;
  bf16* mo1  = p; p += 2097152;
  bf16* hg0  = p; p += 4194304;
  bf16* hg1  = p; p += 4194304;
  float* hb = (float*)(((uintptr_t)p + 255) & ~(uintptr_t)255);
  float* hb0 = hb;
  float* hb1 = hb + 4194304;

  dim3 blk(256);
  prep_weights<<<2304, blk, 0, stream>>>(Wqk, Wv, Wout, Wf1, Wf2,
                                         wqk_t, wv_t, wout_t, wf1_t, wf2_t);
  gemm_k<0><<<dim3(64, 4, 2), blk, 0, stream>>>(x0, x1, nullptr, nullptr, wqk_t, bqk,
                                                qks0, qks1, nullptr, nullptr, nullptr, nullptr, 256);
  gemm_k<1><<<dim3(64, 4, 2), blk, 0, stream>>>(x0, x1, nullptr, nullptr, wv_t, bv,
                                                vT0, vT1, nullptr, nullptr, nullptr, nullptr, 256);
  attn_k<<<dim3(16, 16, 2), blk, 0, stream>>>(qks0, qks1, vT0, vT1, m0, m1);
  gemm_k<2><<<dim3(64, 4, 2), blk, 0, stream>>>(nullptr, nullptr, m0, m1, wout_t, bout,
                                                mo0, mo1, nullptr, nullptr, nullptr, nullptr, 256);
  gemm_k<3><<<dim3(64, 8, 2), blk, 0, stream>>>(x0, x1, mo0, mo1, wf1_t, bf1,
                                                nullptr, nullptr, hb0, hb1, nullptr, nullptr, 512);
  ln_gelu_k<<<dim3(8192, 1, 2), blk, 0, stream>>>(hb, ln_g, ln_b, hg0);
  gemm_k<4><<<dim3(64, 4, 2), blk, 0, stream>>>(nullptr, nullptr, hg0, hg1, wf2_t, bf2,
                                                nullptr, nullptr, y, y + 2097152, x0, x1, 512);
}

// Round 3
// 139.015 us; speedup vs baseline: 1.2310x; 1.0142x over previous
//
#include <hip/hip_runtime.h>
#include <hip/hip_bf16.h>
#include <math.h>

typedef __bf16 bf16;
typedef __attribute__((ext_vector_type(8))) __bf16 bf16x8;
typedef __attribute__((ext_vector_type(4))) __bf16 bf16x4;
typedef __attribute__((ext_vector_type(2))) __bf16 bf16x2;
typedef __attribute__((ext_vector_type(4))) float f32x4;

#define MFMA(a,b,c) __builtin_amdgcn_mfma_f32_16x16x32_bf16(a,b,c,0,0,0)

static constexpr int Bb = 4, Nn = 2048, Hh = 4;
static constexpr int Mrows = Bb * Nn;                 // 8192 rows per sequence
// SS2 = SCALE^0.5 * sqrt(log2(e)) so that S' = S * log2(e); exp2(S') = e^S
static constexpr float SS2 = 0.4246609001440095f;

__device__ __forceinline__ void lds16(const bf16* src, bf16* dst) {
  __builtin_amdgcn_global_load_lds(
      (const __attribute__((address_space(1))) void*)src,
      (__attribute__((address_space(3))) void*)dst, 16, 0, 0);
}

// ---------------- weight prep: f32 [K][N] -> bf16 [N][K]; Wqk|Wv fused ----------------
__global__ __launch_bounds__(256) void prep_weights(
    const float* Wqk, const float* Wv, const float* Wout,
    const float* Wf1, const float* Wf2,
    bf16* wqkv_t, bf16* wout_t, bf16* wf1_t, bf16* wf2_t) {
  int id = blockIdx.x * 256 + threadIdx.x;
  if (id < 65536) { int k = id >> 8, n = id & 255; wqkv_t[n*256 + k] = (bf16)Wqk[id]; return; }
  id -= 65536;
  if (id < 65536) { int k = id >> 8, n = id & 255; wqkv_t[(256 + n)*256 + k] = (bf16)Wv[id]; return; }
  id -= 65536;
  if (id < 65536) { int k = id >> 8, n = id & 255; wout_t[n*256 + k] = (bf16)Wout[id]; return; }
  id -= 65536;
  if (id < 262144) { int k = id >> 9, n = id & 511; wf1_t[n*512 + k] = (bf16)Wf1[id]; return; }
  id -= 262144;
  if (id < 131072) { int k = id >> 8, n = id & 255; wf2_t[n*512 + k] = (bf16)Wf2[id]; return; }
}

// ---------------- generic MFMA GEMM, 128x64 tile, BK=64 ----------------
// MODE 5: A=x f32, fused QK+V projection. cols 0-255 -> qks bf16 [B,H,N,64]
//         (scaled by SS2, bias bqk via `bias`); cols 256-511 -> vT bf16
//         [B,H,64,N] (bias bv via `res`, output via `of` reinterpreted).
// MODE 2: A=m bf16, out = acc+bout    -> mo bf16 [8192,256]
// MODE 3: A=concat(x f32, mo bf16), out = acc+bf1 -> h bf16 [8192,512]
// MODE 4: A=hg bf16, out = acc+bf2+x  -> y f32 [8192,256]
template<int MODE>
__global__ __launch_bounds__(256) void gemm_k(
    const float* Af0, const float* Af1,
    const bf16* Ab0, const bf16* Ab1,
    const bf16* Wt, const float* bias,
    bf16* ob0, bf16* ob1, float* of0, float* of1,
    const float* res0, const float* res1,
    int Kdim) {
  const int z = blockIdx.z;
  const float* Af = z ? Af1 : Af0;
  const bf16*  Ab = z ? Ab1 : Ab0;
  bf16*  ob = z ? ob1 : ob0;
  float* of = z ? of1 : of0;
  const float* res = z ? res1 : res0;

  const int tid = threadIdx.x;
  const int lane = tid & 63;
  const int w = tid >> 6;
  const int wr = w >> 1, wc = w & 1;
  const int m0r = blockIdx.x * 128;
  const int n0 = blockIdx.y * 64;

  __shared__ bf16 At[128][72];
  __shared__ bf16 Bt[64][72];

  f32x4 acc[4][2];
#pragma unroll
  for (int i = 0; i < 4; i++)
#pragma unroll
    for (int j = 0; j < 2; j++) acc[i][j] = f32x4{0.f, 0.f, 0.f, 0.f};

  const int nkc = Kdim >> 6;
  for (int kc = 0; kc < nkc; ++kc) {
    const int k0 = kc * 64;
    if (MODE == 5 || (MODE == 3 && kc < 4)) {
      const int lda = (MODE == 3) ? 256 : Kdim;
#pragma unroll
      for (int i = 0; i < 8; i++) {
        int idx = i * 256 + tid;
        int row = idx >> 4, c4 = (idx & 15) * 4;
        f32x4 v = *reinterpret_cast<const f32x4*>(&Af[(size_t)(m0r + row) * lda + k0 + c4]);
        bf16x4 o; o[0] = (bf16)v[0]; o[1] = (bf16)v[1]; o[2] = (bf16)v[2]; o[3] = (bf16)v[3];
        *reinterpret_cast<bf16x4*>(&At[row][c4]) = o;
      }
    } else {
      const int lda = (MODE == 3) ? 256 : ((MODE == 4) ? 512 : 256);
      const int kk0 = (MODE == 3) ? (k0 - 256) : k0;
#pragma unroll
      for (int i = 0; i < 4; i++) {
        int idx = i * 256 + tid;
        int row = idx >> 3, c8 = (idx & 7) * 8;
        *reinterpret_cast<uint4*>(&At[row][c8]) =
            *reinterpret_cast<const uint4*>(&Ab[(size_t)(m0r + row) * lda + kk0 + c8]);
      }
    }
#pragma unroll
    for (int i = 0; i < 2; i++) {
      int idx = i * 256 + tid;
      int row = idx >> 3, c8 = (idx & 7) * 8;
      *reinterpret_cast<uint4*>(&Bt[row][c8]) =
          *reinterpret_cast<const uint4*>(&Wt[(size_t)(n0 + row) * Kdim + k0 + c8]);
    }
    __syncthreads();
#pragma unroll
    for (int ks = 0; ks < 2; ++ks) {
      bf16x8 af[4], bfr[2];
#pragma unroll
      for (int mf = 0; mf < 4; ++mf)
        af[mf] = *reinterpret_cast<const bf16x8*>(&At[wr*64 + mf*16 + (lane & 15)][ks*32 + (lane >> 4) * 8]);
#pragma unroll
      for (int nf = 0; nf < 2; ++nf)
        bfr[nf] = *reinterpret_cast<const bf16x8*>(&Bt[wc*32 + nf*16 + (lane & 15)][ks*32 + (lane >> 4) * 8]);
#pragma unroll
      for (int mf = 0; mf < 4; ++mf)
#pragma unroll
        for (int nf = 0; nf < 2; ++nf)
          acc[mf][nf] = MFMA(af[mf], bfr[nf], acc[mf][nf]);
    }
    __syncthreads();
  }

#pragma unroll
  for (int mf = 0; mf < 4; ++mf)
#pragma unroll
    for (int nf = 0; nf < 2; ++nf) {
      f32x4 c = acc[mf][nf];
      int cg = n0 + wc*32 + nf*16 + (lane & 15);
#pragma unroll
      for (int r = 0; r < 4; ++r) {
        int rg = m0r + wr*64 + mf*16 + (lane >> 4) * 4 + r;
        if constexpr (MODE == 5) {
          int b = rg >> 11, n = rg & 2047;
          if (cg < 256) {
            float val = (c[r] + bias[cg]) * SS2;
            int h = cg >> 6, dh = cg & 63;
            ob[(((size_t)(b*Hh + h)) * Nn + n) * 64 + dh] = (bf16)val;
          } else {
            int cg2 = cg - 256;
            float val = c[r] + res[cg2];           // res carries bv
            int h = cg2 >> 6, dh = cg2 & 63;
            ((bf16*)of)[(((size_t)(b*Hh + h)) * 64 + dh) * Nn + n] = (bf16)val;
          }
        } else {
          float val = c[r] + bias[cg];
          if constexpr (MODE == 2) {
            ob[(size_t)rg * 256 + cg] = (bf16)val;
          } else if constexpr (MODE == 3) {
            ob[(size_t)rg * 512 + cg] = (bf16)val;
          } else {
            of[(size_t)rg * 256 + cg] = val + res[(size_t)rg * 256 + cg];
          }
        }
      }
    }
}

// ---------------- fused dual-direction attention, pipelined ----------------
// 64 i-rows/block (4 waves x 16), j-tile 64, double-buffered K/V via
// global_load_lds + counted vmcnt + raw barriers, XOR-swizzled LDS,
// swapped QK^T (S^T) so E packs as bf16x2, rowsum via mfma(E, ones).
// Block remap groups all 32 i-blocks of one (bh,dir) on one XCD.
__global__ __launch_bounds__(256, 4) void attn_k(
    const bf16* qks0, const bf16* qks1, const bf16* vT0, const bf16* vT1,
    bf16* m0o, bf16* m1o) {
  const int B = blockIdx.x + 32 * (blockIdx.y + 16 * blockIdx.z);
  const int xcd = B & 7, kk = B >> 3;
  const int group = 4 * xcd + (kk >> 5);     // = dir*16 + bh
  const int it = kk & 31;
  const int bh = group & 15, dir = group >> 4;

  const bf16* Q  = (dir ? qks1 : qks0) + (size_t)bh * (Nn * 64);
  const bf16* Kp = (dir ? qks0 : qks1) + (size_t)bh * (Nn * 64);
  const bf16* Vp = (dir ? vT0  : vT1 ) + (size_t)bh * (64 * Nn);
  bf16* out = dir ? m1o : m0o;
  const int b = bh >> 2, h = bh & 3;

  const int tid = threadIdx.x, lane = tid & 63, w = tid >> 6;
  const int r15 = lane & 15, g = lane >> 4, rb = r15 & 7;
  const int iw = it * 64 + w * 16;           // wave's first q-row

  __shared__ bf16 Kt[2][4096];               // [buf][64 rows x 64 cols], swizzled
  __shared__ bf16 Vt[2][4096];               // [buf][64 d    x 64 j   ], swizzled
  __shared__ bf16 Et[4][1024];               // per-wave [16 i x 64 j], swizzled

  bf16x8 qf[2];
#pragma unroll
  for (int ks = 0; ks < 2; ++ks)
    qf[ks] = *reinterpret_cast<const bf16x8*>(
        &Q[(size_t)(iw + r15) * 64 + ks*32 + g*8]);

  bf16x8 ones;
#pragma unroll
  for (int i = 0; i < 8; ++i) ones[i] = (bf16)1.0f;

  f32x4 acc[4];
  f32x4 rs = f32x4{0.f, 0.f, 0.f, 0.f};
#pragma unroll
  for (int ds = 0; ds < 4; ++ds) acc[ds] = f32x4{0.f, 0.f, 0.f, 0.f};

  // ---- staging setup (pre-swizzled global sources, linear LDS dests) ----
  const int l3 = lane >> 3, l7 = lane & 7;
  const int swz = ((l7 ^ l3) * 8);           // element offset of 16B chunk
  const bf16* ks0 = Kp + (size_t)(w*16 +     l3) * 64 + swz;   // + j0*64
  const bf16* ks1 = Kp + (size_t)(w*16 + 8 + l3) * 64 + swz;
  const bf16* vs0 = Vp + (size_t)(w*16 +     l3) * 2048 + swz; // + j0
  const bf16* vs1 = Vp + (size_t)(w*16 + 8 + l3) * 2048 + swz;
  const int kd0 = (w*16    ) * 64;
  const int kd1 = (w*16 + 8) * 64;

  auto stage = [&](int buf, int j0) {
    lds16(ks0 + (size_t)j0 * 64, &Kt[buf][kd0]);
    lds16(ks1 + (size_t)j0 * 64, &Kt[buf][kd1]);
    lds16(vs0 + j0,              &Vt[buf][kd0]);
    lds16(vs1 + j0,              &Vt[buf][kd1]);
  };

  // ---- read-side swizzle constants ----
  const int rx0 = ((0*4 + g) ^ rb) << 4;
  const int rx1 = ((1*4 + g) ^ rb) << 4;
  const int rowb = r15 << 7;
  const int eb0 = (r15 << 7) + ((g & 1) << 3);
  const int gh = g >> 1;
  int cx[4];
#pragma unroll
  for (int js = 0; js < 4; ++js) cx[js] = ((js*2 + gh) ^ rb) << 4;

  char* ew = (char*)&Et[w][0];

  auto compute_tile = [&](int cur) {
    const char* Kb = (const char*)&Kt[cur][0];
    const char* Vb = (const char*)&Vt[cur][0];
    // --- QK^T (S^T fragments: rows j, cols i), S pre-scaled by log2e ---
    f32x4 st[4];
    __builtin_amdgcn_s_setprio(1);
#pragma unroll
    for (int js = 0; js < 4; ++js) {
      bf16x8 k0 = *reinterpret_cast<const bf16x8*>(Kb + js*2048 + rowb + rx0);
      bf16x8 k1 = *reinterpret_cast<const bf16x8*>(Kb + js*2048 + rowb + rx1);
      f32x4 t{0.f, 0.f, 0.f, 0.f};
      t = MFMA(k0, qf[0], t);
      t = MFMA(k1, qf[1], t);
      st[js] = t;
    }
    __builtin_amdgcn_s_setprio(0);
    // --- exp2 + pack pairs + swizzled E write ---
#pragma unroll
    for (int js = 0; js < 4; ++js) {
      float e0 = __builtin_amdgcn_exp2f(st[js][0]);
      float e1 = __builtin_amdgcn_exp2f(st[js][1]);
      float e2 = __builtin_amdgcn_exp2f(st[js][2]);
      float e3 = __builtin_amdgcn_exp2f(st[js][3]);
      bf16x2 p0; p0[0] = (bf16)e0; p0[1] = (bf16)e1;
      bf16x2 p1; p1[0] = (bf16)e2; p1[1] = (bf16)e3;
      *reinterpret_cast<bf16x2*>(ew + eb0 + cx[js]    ) = p0;
      *reinterpret_cast<bf16x2*>(ew + eb0 + cx[js] + 4) = p1;
    }
    // --- PV + rowsum ---
    bf16x8 ef[2];
    ef[0] = *reinterpret_cast<const bf16x8*>(ew + rowb + rx0);
    ef[1] = *reinterpret_cast<const bf16x8*>(ew + rowb + rx1);
    __builtin_amdgcn_s_setprio(1);
    rs = MFMA(ef[0], ones, rs);
    rs = MFMA(ef[1], ones, rs);
#pragma unroll
    for (int ds = 0; ds < 4; ++ds) {
      bf16x8 v0 = *reinterpret_cast<const bf16x8*>(Vb + ds*2048 + rowb + rx0);
      bf16x8 v1 = *reinterpret_cast<const bf16x8*>(Vb + ds*2048 + rowb + rx1);
      acc[ds] = MFMA(ef[0], v0, acc[ds]);
      acc[ds] = MFMA(ef[1], v1, acc[ds]);
    }
    __builtin_amdgcn_s_setprio(0);
  };

  // ---- pipelined main loop: 32 j-tiles, last one peeled ----
  stage(0, 0);
  int cur = 0;
  for (int jt = 0; jt < 31; ++jt) {
    stage(cur ^ 1, (jt + 1) << 6);
    asm volatile("s_waitcnt vmcnt(4)" ::: "memory");
    __builtin_amdgcn_sched_barrier(0);
    __builtin_amdgcn_s_barrier();
    __builtin_amdgcn_sched_barrier(0);
    compute_tile(cur);
    asm volatile("s_waitcnt lgkmcnt(0)" ::: "memory");
    __builtin_amdgcn_sched_barrier(0);
    __builtin_amdgcn_s_barrier();
    __builtin_amdgcn_sched_barrier(0);
    cur ^= 1;
  }
  asm volatile("s_waitcnt vmcnt(0)" ::: "memory");
  __builtin_amdgcn_sched_barrier(0);
  __builtin_amdgcn_s_barrier();
  __builtin_amdgcn_sched_barrier(0);
  compute_tile(cur);

  // ---- epilogue: divide by rowsum, write out ----
  f32x4 inv;
#pragma unroll
  for (int r = 0; r < 4; ++r) inv[r] = 1.0f / rs[r];
#pragma unroll
  for (int ds = 0; ds < 4; ++ds)
#pragma unroll
    for (int r = 0; r < 4; ++r) {
      int row = iw + 4*g + r;
      int col = h*64 + ds*16 + r15;
      out[((size_t)b * Nn + row) * 256 + col] = (bf16)(acc[ds][r] * inv[r]);
    }
}

// ---------------- LayerNorm + exact GELU, in-place on bf16 h ----------------
__global__ __launch_bounds__(256) void ln_gelu_k(
    bf16* hg, const float* g, const float* bb) {
  const size_t row = blockIdx.x;
  const int tid = threadIdx.x;
  bf16* hr = hg + row * 512;
  bf16x2 v2 = *reinterpret_cast<const bf16x2*>(&hr[tid * 2]);
  float vx = (float)v2[0], vy = (float)v2[1];
  float s = vx + vy;
  float sq = vx * vx + vy * vy;
#pragma unroll
  for (int m = 1; m < 64; m <<= 1) {
    s += __shfl_xor(s, m);
    sq += __shfl_xor(sq, m);
  }
  __shared__ float ws_s[4], ws_q[4];
  int w = tid >> 6, lane = tid & 63;
  if (lane == 0) { ws_s[w] = s; ws_q[w] = sq; }
  __syncthreads();
  s = ws_s[0] + ws_s[1] + ws_s[2] + ws_s[3];
  sq = ws_q[0] + ws_q[1] + ws_q[2] + ws_q[3];
  float mu = s * (1.f / 512.f);
  float var = sq * (1.f / 512.f) - mu * mu;
  float rsv = rsqrtf(var + 1e-5f);
  bf16x2 o2;
#pragma unroll
  for (int i = 0; i < 2; i++) {
    int c = tid * 2 + i;
    float xv = i ? vy : vx;
    float xn = (xv - mu) * rsv * g[c] + bb[c];
    float ge = 0.5f * xn * (1.f + erff(xn * 0.70710678118f));
    o2[i] = (bf16)ge;
  }
  *reinterpret_cast<bf16x2*>(&hr[tid * 2]) = o2;
}

extern "C" void kernel_launch(void* const* d_in, const int* in_sizes, int n_in,
                              void* d_out, int out_size, void* d_ws, size_t ws_size,
                              hipStream_t stream) {
  (void)in_sizes; (void)n_in; (void)out_size; (void)ws_size;
  const float* x0   = (const float*)d_in[0];
  const float* x1   = (const float*)d_in[1];
  const float* Wqk  = (const float*)d_in[2];
  const float* bqk  = (const float*)d_in[3];
  const float* Wv   = (const float*)d_in[4];
  const float* bv   = (const float*)d_in[5];
  const float* Wout = (const float*)d_in[6];
  const float* bout = (const float*)d_in[7];
  const float* Wf1  = (const float*)d_in[8];
  const float* bf1  = (const float*)d_in[9];
  const float* ln_g = (const float*)d_in[10];
  const float* ln_b = (const float*)d_in[11];
  const float* Wf2  = (const float*)d_in[12];
  const float* bf2  = (const float*)d_in[13];
  float* y = (float*)d_out;

  bf16* p = (bf16*)d_ws;
  bf16* wqkv_t = p; p += 131072;
  bf16* wout_t = p; p += 65536;
  bf16* wf1_t  = p; p += 262144;
  bf16* wf2_t  = p; p += 131072;
  bf16* qks0 = p; p += 2097152;
  bf16* qks1 = p; p += 2097152;
  bf16* vT0  = p; p += 2097152;
  bf16* vT1  = p; p += 2097152;
  bf16* m0   = p; p += 2097152;
  bf16* m1   = p; p += 2097152;
  bf16* mo0  = p; p += 2097152;
  bf16* mo1  = p; p += 2097152;
  bf16* hg0  = p; p += 4194304;
  bf16* hg1  = p; p += 4194304;

  dim3 blk(256);
  prep_weights<<<2304, blk, 0, stream>>>(Wqk, Wv, Wout, Wf1, Wf2,
                                         wqkv_t, wout_t, wf1_t, wf2_t);
  gemm_k<5><<<dim3(64, 8, 2), blk, 0, stream>>>(x0, x1, nullptr, nullptr, wqkv_t, bqk,
                                                qks0, qks1, (float*)vT0, (float*)vT1, bv, bv, 256);
  attn_k<<<dim3(32, 16, 2), blk, 0, stream>>>(qks0, qks1, vT0, vT1, m0, m1);
  gemm_k<2><<<dim3(64, 4, 2), blk, 0, stream>>>(nullptr, nullptr, m0, m1, wout_t, bout,
                                                mo0, mo1, nullptr, nullptr, nullptr, nullptr, 256);
  gemm_k<3><<<dim3(64, 8, 2), blk, 0, stream>>>(x0, x1, mo0, mo1, wf1_t, bf1,
                                                hg0, hg1, nullptr, nullptr, nullptr, nullptr, 512);
  ln_gelu_k<<<dim3(16384), blk, 0, stream>>>(hg0, ln_g, ln_b);
  gemm_k<4><<<dim3(64, 4, 2), blk, 0, stream>>>(nullptr, nullptr, hg0, hg1, wf2_t, bf2,
                                                nullptr, nullptr, y, y + 2097152, x0, x1, 512);
}

// Round 4
// 132.323 us; speedup vs baseline: 1.2932x; 1.0506x over previous
//
#include <hip/hip_runtime.h>
#include <hip/hip_bf16.h>
#include <math.h>

typedef __bf16 bf16;
typedef __attribute__((ext_vector_type(8))) __bf16 bf16x8;
typedef __attribute__((ext_vector_type(4))) __bf16 bf16x4;
typedef __attribute__((ext_vector_type(2))) __bf16 bf16x2;
typedef __attribute__((ext_vector_type(4))) float f32x4;

#define MFMA(a,b,c) __builtin_amdgcn_mfma_f32_16x16x32_bf16(a,b,c,0,0,0)

static constexpr int Bb = 4, Nn = 2048, Hh = 4;
static constexpr int Mrows = Bb * Nn;                 // 8192 rows per sequence
// SS2 = SCALE^0.5 * sqrt(log2(e)) so that S' = S * log2(e); exp2(S') = e^S
static constexpr float SS2 = 0.4246609001440095f;

__device__ __forceinline__ void lds16(const bf16* src, bf16* dst) {
  __builtin_amdgcn_global_load_lds(
      (const __attribute__((address_space(1))) void*)src,
      (__attribute__((address_space(3))) void*)dst, 16, 0, 0);
}

// ---------------- prep: weights f32 [K][N] -> bf16 [N][K]; x -> bf16 ----------------
__global__ __launch_bounds__(256) void prep_k(
    const float* Wqk, const float* Wv, const float* Wout,
    const float* Wf1, const float* Wf2, const float* x0, const float* x1,
    bf16* wqkv_t, bf16* wout_t, bf16* wf1_t, bf16* wf2_t,
    bf16* xb0, bf16* xb1) {
  int id = blockIdx.x * 256 + threadIdx.x;
  if (id < 65536) { int k = id >> 8, n = id & 255; wqkv_t[n*256 + k] = (bf16)Wqk[id]; return; }
  id -= 65536;
  if (id < 65536) { int k = id >> 8, n = id & 255; wqkv_t[(256 + n)*256 + k] = (bf16)Wv[id]; return; }
  id -= 65536;
  if (id < 65536) { int k = id >> 8, n = id & 255; wout_t[n*256 + k] = (bf16)Wout[id]; return; }
  id -= 65536;
  if (id < 262144) { int k = id >> 9, n = id & 511; wf1_t[n*512 + k] = (bf16)Wf1[id]; return; }
  id -= 262144;
  if (id < 131072) { int k = id >> 8, n = id & 255; wf2_t[n*512 + k] = (bf16)Wf2[id]; return; }
  id -= 131072;
  if (id < 1048576) {                               // x conversion, f32x4 per id
    const float* xs = (id < 524288) ? x0 : x1;
    bf16* xd = (id < 524288) ? xb0 : xb1;
    int j = (id < 524288) ? id : id - 524288;
    f32x4 v = *reinterpret_cast<const f32x4*>(&xs[(size_t)j * 4]);
    bf16x4 o; o[0] = (bf16)v[0]; o[1] = (bf16)v[1]; o[2] = (bf16)v[2]; o[3] = (bf16)v[3];
    *reinterpret_cast<bf16x4*>(&xd[(size_t)j * 4]) = o;
  }
}

// ---------------- pipelined MFMA GEMM, 128x64 tile, BK=64, dbuf + lds16 ----------------
// MODE 5: A=xb, fused QK+V proj. cols 0-255 -> qks bf16 [B,H,N,64] (scale SS2,
//         bias bqk); cols 256-511 -> vT bf16 [B,H,64,N] (bias bv via res).
// MODE 2: A=m bf16,           out = acc+bout        -> mo bf16 [8192,256]
// MODE 3: A=xb|mo (concat),   out = acc+bf1         -> h  bf16 [8192,512]
// MODE 4: A=hg bf16 (lda512), out = acc+bf2+x (f32) -> y  f32  [8192,256]
template<int MODE>
__global__ __launch_bounds__(256, 3) void gemm_k(
    const bf16* Aa0, const bf16* Aa1, const bf16* Ac0, const bf16* Ac1,
    const bf16* Wt, const float* bias,
    bf16* ob0, bf16* ob1, float* of0, float* of1,
    const float* res0, const float* res1) {
  constexpr int KD  = (MODE == 3 || MODE == 4) ? 512 : 256;
  constexpr int LDA = (MODE == 4) ? 512 : 256;
  constexpr int NKC = KD / 64;

  const int z = blockIdx.z;
  const bf16* Aa = z ? Aa1 : Aa0;
  const bf16* Ac = z ? Ac1 : Ac0;
  bf16*  ob = z ? ob1 : ob0;
  float* of = z ? of1 : of0;
  const float* res = z ? res1 : res0;

  const int tid = threadIdx.x;
  const int lane = tid & 63;
  const int w = tid >> 6;
  const int wr = w >> 1, wc = w & 1;
  const int m0r = blockIdx.x * 128;
  const int n0 = blockIdx.y * 64;
  const int r15 = lane & 15, g = lane >> 4, rb = r15 & 7;
  const int l3 = lane >> 3, l7 = lane & 7;
  const int swzc = (l7 ^ l3) * 8;

  __shared__ bf16 At[2][8192];    // [buf][128 rows x 64 cols], XOR-swizzled
  __shared__ bf16 Bt[2][4096];    // [buf][ 64 rows x 64 cols], XOR-swizzled

  const bf16* aA = Aa + (size_t)(m0r + w*32 + l3) * LDA + swzc;
  const bf16* aC = (MODE == 3) ? (Ac + (size_t)(m0r + w*32 + l3) * 256 + swzc) : nullptr;
  const bf16* bB = Wt + (size_t)(n0 + w*16 + l3) * KD + swzc;
  const int adst = (w*32) * 64;   // wave-uniform LDS element offsets
  const int bdst = (w*16) * 64;

  auto stage = [&](int buf, int kc) {
    const bf16* ab; int kcol;
    if constexpr (MODE == 3) {
      if (kc < 4) { ab = aA; kcol = kc * 64; } else { ab = aC; kcol = (kc - 4) * 64; }
    } else { ab = aA; kcol = kc * 64; }
#pragma unroll
    for (int i = 0; i < 4; i++)
      lds16(ab + kcol + (size_t)i * 8 * LDA, &At[buf][adst + i*512]);
#pragma unroll
    for (int i = 0; i < 2; i++)
      lds16(bB + kc*64 + (size_t)i * 8 * KD, &Bt[buf][bdst + i*512]);
  };

  f32x4 acc[4][2];
#pragma unroll
  for (int i = 0; i < 4; i++)
#pragma unroll
    for (int j = 0; j < 2; j++) acc[i][j] = f32x4{0.f, 0.f, 0.f, 0.f};

  const int rx0 = ((0*4 + g) ^ rb) << 4;
  const int rx1 = ((1*4 + g) ^ rb) << 4;

  auto compute = [&](int cur) {
    const char* Ap = (const char*)&At[cur][0];
    const char* Bp = (const char*)&Bt[cur][0];
    __builtin_amdgcn_s_setprio(1);
#pragma unroll
    for (int ks = 0; ks < 2; ++ks) {
      const int rx = ks ? rx1 : rx0;
      bf16x8 af[4], bfr[2];
#pragma unroll
      for (int mf = 0; mf < 4; ++mf)
        af[mf] = *reinterpret_cast<const bf16x8*>(Ap + (wr*64 + mf*16 + r15) * 128 + rx);
#pragma unroll
      for (int nf = 0; nf < 2; ++nf)
        bfr[nf] = *reinterpret_cast<const bf16x8*>(Bp + (wc*32 + nf*16 + r15) * 128 + rx);
#pragma unroll
      for (int mf = 0; mf < 4; ++mf)
#pragma unroll
        for (int nf = 0; nf < 2; ++nf)
          acc[mf][nf] = MFMA(af[mf], bfr[nf], acc[mf][nf]);
    }
    __builtin_amdgcn_s_setprio(0);
  };

  stage(0, 0);
  int cur = 0;
  for (int kc = 0; kc < NKC - 1; ++kc) {
    stage(cur ^ 1, kc + 1);
    asm volatile("s_waitcnt vmcnt(6)" ::: "memory");
    __builtin_amdgcn_sched_barrier(0);
    __builtin_amdgcn_s_barrier();
    __builtin_amdgcn_sched_barrier(0);
    compute(cur);
    asm volatile("s_waitcnt lgkmcnt(0)" ::: "memory");
    __builtin_amdgcn_sched_barrier(0);
    __builtin_amdgcn_s_barrier();
    __builtin_amdgcn_sched_barrier(0);
    cur ^= 1;
  }
  asm volatile("s_waitcnt vmcnt(0)" ::: "memory");
  __builtin_amdgcn_sched_barrier(0);
  __builtin_amdgcn_s_barrier();
  __builtin_amdgcn_sched_barrier(0);
  compute(cur);

  // ---- epilogue ----
#pragma unroll
  for (int mf = 0; mf < 4; ++mf)
#pragma unroll
    for (int nf = 0; nf < 2; ++nf) {
      f32x4 c = acc[mf][nf];
      int cg = n0 + wc*32 + nf*16 + r15;
#pragma unroll
      for (int r = 0; r < 4; ++r) {
        int rg = m0r + wr*64 + mf*16 + g*4 + r;
        if constexpr (MODE == 5) {
          int b = rg >> 11, n = rg & 2047;
          if (cg < 256) {
            float val = (c[r] + bias[cg]) * SS2;
            int h = cg >> 6, dh = cg & 63;
            ob[(((size_t)(b*Hh + h)) * Nn + n) * 64 + dh] = (bf16)val;
          } else {
            int cg2 = cg - 256;
            float val = c[r] + res[cg2];           // res carries bv
            int h = cg2 >> 6, dh = cg2 & 63;
            ((bf16*)of)[(((size_t)(b*Hh + h)) * 64 + dh) * Nn + n] = (bf16)val;
          }
        } else {
          float val = c[r] + bias[cg];
          if constexpr (MODE == 2) {
            ob[(size_t)rg * 256 + cg] = (bf16)val;
          } else if constexpr (MODE == 3) {
            ob[(size_t)rg * 512 + cg] = (bf16)val;
          } else {
            of[(size_t)rg * 256 + cg] = val + res[(size_t)rg * 256 + cg];
          }
        }
      }
    }
}

// ---------------- fused dual-direction attention, pipelined ----------------
// 128 i-rows/block (4 waves x 32), j-tile 64, double-buffered K/V via
// global_load_lds + counted vmcnt + raw barriers, XOR-swizzled LDS,
// swapped QK^T (S^T) so E packs as bf16x2, rowsum via mfma(E, ones).
// Block remap groups the 16 i-blocks of each (bh,dir) on one XCD.
__global__ __launch_bounds__(256, 2) void attn_k(
    const bf16* qks0, const bf16* qks1, const bf16* vT0, const bf16* vT1,
    bf16* m0o, bf16* m1o) {
  const int B = blockIdx.x + 16 * (blockIdx.y + 16 * blockIdx.z);
  const int xcd = B & 7, kk = B >> 3;          // kk 0..63
  const int group = 4 * xcd + (kk >> 4);       // 0..31 = dir*16 + bh
  const int it = kk & 15;
  const int bh = group & 15, dir = group >> 4;

  const bf16* Q  = (dir ? qks1 : qks0) + (size_t)bh * (Nn * 64);
  const bf16* Kp = (dir ? qks0 : qks1) + (size_t)bh * (Nn * 64);
  const bf16* Vp = (dir ? vT0  : vT1 ) + (size_t)bh * (64 * Nn);
  bf16* out = dir ? m1o : m0o;
  const int b = bh >> 2, h = bh & 3;

  const int tid = threadIdx.x, lane = tid & 63, w = tid >> 6;
  const int r15 = lane & 15, g = lane >> 4, rb = r15 & 7;
  const int iw = it * 128 + w * 32;            // wave's first q-row

  __shared__ bf16 Kt[2][4096];                 // [buf][64 j x 64 d], swizzled
  __shared__ bf16 Vt[2][4096];                 // [buf][64 d x 64 j], swizzled
  __shared__ bf16 Et[4][2048];                 // per-wave [32 i x 64 j], swizzled

  bf16x8 qf[2][2];
#pragma unroll
  for (int f = 0; f < 2; ++f)
#pragma unroll
    for (int ks = 0; ks < 2; ++ks)
      qf[f][ks] = *reinterpret_cast<const bf16x8*>(
          &Q[(size_t)(iw + f*16 + r15) * 64 + ks*32 + g*8]);

  bf16x8 ones;
#pragma unroll
  for (int i = 0; i < 8; ++i) ones[i] = (bf16)1.0f;

  f32x4 acc[2][4];
  f32x4 rs[2];
#pragma unroll
  for (int f = 0; f < 2; ++f) {
    rs[f] = f32x4{0.f, 0.f, 0.f, 0.f};
#pragma unroll
    for (int ds = 0; ds < 4; ++ds) acc[f][ds] = f32x4{0.f, 0.f, 0.f, 0.f};
  }

  // ---- staging (pre-swizzled global sources, linear LDS dests) ----
  const int l3 = lane >> 3, l7 = lane & 7;
  const int swz = ((l7 ^ l3) * 8);
  const bf16* ks0 = Kp + (size_t)(w*16 +     l3) * 64 + swz;
  const bf16* ks1 = Kp + (size_t)(w*16 + 8 + l3) * 64 + swz;
  const bf16* vs0 = Vp + (size_t)(w*16 +     l3) * 2048 + swz;
  const bf16* vs1 = Vp + (size_t)(w*16 + 8 + l3) * 2048 + swz;
  const int kd0 = (w*16    ) * 64;
  const int kd1 = (w*16 + 8) * 64;

  auto stage = [&](int buf, int j0) {
    lds16(ks0 + (size_t)j0 * 64, &Kt[buf][kd0]);
    lds16(ks1 + (size_t)j0 * 64, &Kt[buf][kd1]);
    lds16(vs0 + j0,              &Vt[buf][kd0]);
    lds16(vs1 + j0,              &Vt[buf][kd1]);
  };

  const int rx0 = ((0*4 + g) ^ rb) << 4;
  const int rx1 = ((1*4 + g) ^ rb) << 4;
  const int rowb = r15 << 7;
  const int eb0 = (r15 << 7) + ((g & 1) << 3);
  const int eb1 = eb0 + (16 << 7);
  const int gh = g >> 1;
  int cx[4];
#pragma unroll
  for (int js = 0; js < 4; ++js) cx[js] = ((js*2 + gh) ^ rb) << 4;

  char* ew = (char*)&Et[w][0];

  auto compute_tile = [&](int cur) {
    const char* Kb = (const char*)&Kt[cur][0];
    const char* Vb = (const char*)&Vt[cur][0];
    f32x4 st[2][4];
    __builtin_amdgcn_s_setprio(1);
#pragma unroll
    for (int js = 0; js < 4; ++js) {
      bf16x8 k0 = *reinterpret_cast<const bf16x8*>(Kb + js*2048 + rowb + rx0);
      bf16x8 k1 = *reinterpret_cast<const bf16x8*>(Kb + js*2048 + rowb + rx1);
#pragma unroll
      for (int f = 0; f < 2; ++f) {
        f32x4 t{0.f, 0.f, 0.f, 0.f};
        t = MFMA(k0, qf[f][0], t);
        t = MFMA(k1, qf[f][1], t);
        st[f][js] = t;
      }
    }
    __builtin_amdgcn_s_setprio(0);
#pragma unroll
    for (int f = 0; f < 2; ++f) {
      const int ebf = f ? eb1 : eb0;
#pragma unroll
      for (int js = 0; js < 4; ++js) {
        float e0 = __builtin_amdgcn_exp2f(st[f][js][0]);
        float e1 = __builtin_amdgcn_exp2f(st[f][js][1]);
        float e2 = __builtin_amdgcn_exp2f(st[f][js][2]);
        float e3 = __builtin_amdgcn_exp2f(st[f][js][3]);
        bf16x2 p0; p0[0] = (bf16)e0; p0[1] = (bf16)e1;
        bf16x2 p1; p1[0] = (bf16)e2; p1[1] = (bf16)e3;
        *reinterpret_cast<bf16x2*>(ew + ebf + cx[js]    ) = p0;
        *reinterpret_cast<bf16x2*>(ew + ebf + cx[js] + 4) = p1;
      }
    }
    bf16x8 ef[2][2];
#pragma unroll
    for (int f = 0; f < 2; ++f) {
      ef[f][0] = *reinterpret_cast<const bf16x8*>(ew + f*2048 + rowb + rx0);
      ef[f][1] = *reinterpret_cast<const bf16x8*>(ew + f*2048 + rowb + rx1);
    }
    __builtin_amdgcn_s_setprio(1);
#pragma unroll
    for (int f = 0; f < 2; ++f) {
      rs[f] = MFMA(ef[f][0], ones, rs[f]);
      rs[f] = MFMA(ef[f][1], ones, rs[f]);
    }
#pragma unroll
    for (int ds = 0; ds < 4; ++ds) {
      bf16x8 v0 = *reinterpret_cast<const bf16x8*>(Vb + ds*2048 + rowb + rx0);
      bf16x8 v1 = *reinterpret_cast<const bf16x8*>(Vb + ds*2048 + rowb + rx1);
#pragma unroll
      for (int f = 0; f < 2; ++f) {
        acc[f][ds] = MFMA(ef[f][0], v0, acc[f][ds]);
        acc[f][ds] = MFMA(ef[f][1], v1, acc[f][ds]);
      }
    }
    __builtin_amdgcn_s_setprio(0);
  };

  stage(0, 0);
  int cur = 0;
  for (int jt = 0; jt < 31; ++jt) {
    stage(cur ^ 1, (jt + 1) << 6);
    asm volatile("s_waitcnt vmcnt(4)" ::: "memory");
    __builtin_amdgcn_sched_barrier(0);
    __builtin_amdgcn_s_barrier();
    __builtin_amdgcn_sched_barrier(0);
    compute_tile(cur);
    asm volatile("s_waitcnt lgkmcnt(0)" ::: "memory");
    __builtin_amdgcn_sched_barrier(0);
    __builtin_amdgcn_s_barrier();
    __builtin_amdgcn_sched_barrier(0);
    cur ^= 1;
  }
  asm volatile("s_waitcnt vmcnt(0)" ::: "memory");
  __builtin_amdgcn_sched_barrier(0);
  __builtin_amdgcn_s_barrier();
  __builtin_amdgcn_sched_barrier(0);
  compute_tile(cur);

#pragma unroll
  for (int f = 0; f < 2; ++f) {
    f32x4 inv;
#pragma unroll
    for (int r = 0; r < 4; ++r) inv[r] = 1.0f / rs[f][r];
#pragma unroll
    for (int ds = 0; ds < 4; ++ds)
#pragma unroll
      for (int r = 0; r < 4; ++r) {
        int row = iw + f*16 + 4*g + r;
        int col = h*64 + ds*16 + r15;
        out[((size_t)b * Nn + row) * 256 + col] = (bf16)(acc[f][ds][r] * inv[r]);
      }
  }
}

// ---------------- LayerNorm + exact GELU, in-place on bf16 h ----------------
__global__ __launch_bounds__(256) void ln_gelu_k(
    bf16* hg, const float* g, const float* bb) {
  const size_t row = blockIdx.x;
  const int tid = threadIdx.x;
  bf16* hr = hg + row * 512;
  bf16x2 v2 = *reinterpret_cast<const bf16x2*>(&hr[tid * 2]);
  float vx = (float)v2[0], vy = (float)v2[1];
  float s = vx + vy;
  float sq = vx * vx + vy * vy;
#pragma unroll
  for (int m = 1; m < 64; m <<= 1) {
    s += __shfl_xor(s, m);
    sq += __shfl_xor(sq, m);
  }
  __shared__ float ws_s[4], ws_q[4];
  int w = tid >> 6, lane = tid & 63;
  if (lane == 0) { ws_s[w] = s; ws_q[w] = sq; }
  __syncthreads();
  s = ws_s[0] + ws_s[1] + ws_s[2] + ws_s[3];
  sq = ws_q[0] + ws_q[1] + ws_q[2] + ws_q[3];
  float mu = s * (1.f / 512.f);
  float var = sq * (1.f / 512.f) - mu * mu;
  float rsv = rsqrtf(var + 1e-5f);
  bf16x2 o2;
#pragma unroll
  for (int i = 0; i < 2; i++) {
    int c = tid * 2 + i;
    float xv = i ? vy : vx;
    float xn = (xv - mu) * rsv * g[c] + bb[c];
    float ge = 0.5f * xn * (1.f + erff(xn * 0.70710678118f));
    o2[i] = (bf16)ge;
  }
  *reinterpret_cast<bf16x2*>(&hr[tid * 2]) = o2;
}

extern "C" void kernel_launch(void* const* d_in, const int* in_sizes, int n_in,
                              void* d_out, int out_size, void* d_ws, size_t ws_size,
                              hipStream_t stream) {
  (void)in_sizes; (void)n_in; (void)out_size; (void)ws_size;
  const float* x0   = (const float*)d_in[0];
  const float* x1   = (const float*)d_in[1];
  const float* Wqk  = (const float*)d_in[2];
  const float* bqk  = (const float*)d_in[3];
  const float* Wv   = (const float*)d_in[4];
  const float* bv   = (const float*)d_in[5];
  const float* Wout = (const float*)d_in[6];
  const float* bout = (const float*)d_in[7];
  const float* Wf1  = (const float*)d_in[8];
  const float* bf1  = (const float*)d_in[9];
  const float* ln_g = (const float*)d_in[10];
  const float* ln_b = (const float*)d_in[11];
  const float* Wf2  = (const float*)d_in[12];
  const float* bf2  = (const float*)d_in[13];
  float* y = (float*)d_out;

  bf16* p = (bf16*)d_ws;
  bf16* wqkv_t = p; p += 131072;
  bf16* wout_t = p; p += 65536;
  bf16* wf1_t  = p; p += 262144;
  bf16* wf2_t  = p; p += 131072;
  bf16* xb0  = p; p += 2097152;
  bf16* xb1  = p; p += 2097152;
  bf16* qks0 = p; p += 2097152;
  bf16* qks1 = p; p += 2097152;
  bf16* vT0  = p; p += 2097152;
  bf16* vT1  = p; p += 2097152;
  bf16* m0   = p; p += 2097152;
  bf16* m1   = p; p += 2097152;
  bf16* mo0  = p; p += 2097152;
  bf16* mo1  = p; p += 2097152;
  bf16* hg0  = p; p += 4194304;
  bf16* hg1  = p; p += 4194304;

  dim3 blk(256);
  prep_k<<<6400, blk, 0, stream>>>(Wqk, Wv, Wout, Wf1, Wf2, x0, x1,
                                   wqkv_t, wout_t, wf1_t, wf2_t, xb0, xb1);
  gemm_k<5><<<dim3(64, 8, 2), blk, 0, stream>>>(xb0, xb1, nullptr, nullptr, wqkv_t, bqk,
                                                qks0, qks1, (float*)vT0, (float*)vT1, bv, bv);
  attn_k<<<dim3(16, 16, 2), blk, 0, stream>>>(qks0, qks1, vT0, vT1, m0, m1);
  gemm_k<2><<<dim3(64, 4, 2), blk, 0, stream>>>(m0, m1, nullptr, nullptr, wout_t, bout,
                                                mo0, mo1, nullptr, nullptr, nullptr, nullptr);
  gemm_k<3><<<dim3(64, 8, 2), blk, 0, stream>>>(xb0, xb1, mo0, mo1, wf1_t, bf1,
                                                hg0, hg1, nullptr, nullptr, nullptr, nullptr);
  ln_gelu_k<<<dim3(16384), blk, 0, stream>>>(hg0, ln_g, ln_b);
  gemm_k<4><<<dim3(64, 4, 2), blk, 0, stream>>>(hg0, hg1, nullptr, nullptr, wf2_t, bf2,
                                                nullptr, nullptr, y, y + 2097152, x0, x1);
}

// Round 5
// 129.703 us; speedup vs baseline: 1.3193x; 1.0202x over previous
//
#include <hip/hip_runtime.h>
#include <hip/hip_bf16.h>
#include <math.h>

typedef __bf16 bf16;
typedef __attribute__((ext_vector_type(8))) __bf16 bf16x8;
typedef __attribute__((ext_vector_type(4))) __bf16 bf16x4;
typedef __attribute__((ext_vector_type(2))) __bf16 bf16x2;
typedef __attribute__((ext_vector_type(4))) float f32x4;
typedef __attribute__((ext_vector_type(16))) float f32x16;
typedef __attribute__((ext_vector_type(4))) unsigned u32x4;

#define MFMA(a,b,c)   __builtin_amdgcn_mfma_f32_16x16x32_bf16(a,b,c,0,0,0)
#define MFMA32(a,b,c) __builtin_amdgcn_mfma_f32_32x32x16_bf16(a,b,c,0,0,0)

static constexpr int Bb = 4, Nn = 2048, Hh = 4;
static constexpr int Mrows = Bb * Nn;
// SS2 = SCALE^0.5 * sqrt(log2(e)) so that S' = S * log2(e); exp2(S') = e^S
static constexpr float SS2 = 0.4246609001440095f;

__device__ __forceinline__ void lds16(const bf16* src, bf16* dst) {
  __builtin_amdgcn_global_load_lds(
      (const __attribute__((address_space(1))) void*)src,
      (__attribute__((address_space(3))) void*)dst, 16, 0, 0);
}

__device__ __forceinline__ f32x16 zero16() {
  f32x16 t;
#pragma unroll
  for (int i = 0; i < 16; ++i) t[i] = 0.f;
  return t;
}

// ---------------- prep: weights f32 [K][N] -> bf16 [N][K]; x -> bf16 ----------------
__global__ __launch_bounds__(256) void prep_k(
    const float* Wqk, const float* Wv, const float* Wout,
    const float* Wf1, const float* Wf2, const float* x0, const float* x1,
    bf16* wqkv_t, bf16* wout_t, bf16* wf1_t, bf16* wf2_t,
    bf16* xb0, bf16* xb1) {
  int id = blockIdx.x * 256 + threadIdx.x;
  if (id < 65536) { int k = id >> 8, n = id & 255; wqkv_t[n*256 + k] = (bf16)Wqk[id]; return; }
  id -= 65536;
  if (id < 65536) { int k = id >> 8, n = id & 255; wqkv_t[(256 + n)*256 + k] = (bf16)Wv[id]; return; }
  id -= 65536;
  if (id < 65536) { int k = id >> 8, n = id & 255; wout_t[n*256 + k] = (bf16)Wout[id]; return; }
  id -= 65536;
  if (id < 262144) { int k = id >> 9, n = id & 511; wf1_t[n*512 + k] = (bf16)Wf1[id]; return; }
  id -= 262144;
  if (id < 131072) { int k = id >> 8, n = id & 255; wf2_t[n*512 + k] = (bf16)Wf2[id]; return; }
  id -= 131072;
  if (id < 1048576) {                               // x conversion, f32x4 per id
    const float* xs = (id < 524288) ? x0 : x1;
    bf16* xd = (id < 524288) ? xb0 : xb1;
    int j = (id < 524288) ? id : id - 524288;
    f32x4 v = *reinterpret_cast<const f32x4*>(&xs[(size_t)j * 4]);
    bf16x4 o; o[0] = (bf16)v[0]; o[1] = (bf16)v[1]; o[2] = (bf16)v[2]; o[3] = (bf16)v[3];
    *reinterpret_cast<bf16x4*>(&xd[(size_t)j * 4]) = o;
  }
}

// ---------------- pipelined MFMA GEMM, 128x64 tile, BK=64, dbuf + lds16 ----------------
// MODE 5: A=xb, fused QK+V proj. cols 0-255 -> qks bf16 [B,H,N,64] (scale SS2,
//         bias bqk); cols 256-511 -> vT bf16 [B,H,64,N] (bias bv via res).
// MODE 2: A=m bf16,           out = acc+bout          -> mo bf16 [8192,256]
// MODE 3: A=xb|mo (concat),   out = acc+bf1           -> h  bf16 [8192,512]
// MODE 4: A=hg bf16 (lda512), out = acc+bf2+xb (Ac)   -> y  f32  [8192,256]
template<int MODE>
__global__ __launch_bounds__(256, 3) void gemm_k(
    const bf16* Aa0, const bf16* Aa1, const bf16* Ac0, const bf16* Ac1,
    const bf16* Wt, const float* bias,
    bf16* ob0, bf16* ob1, float* of0, float* of1,
    const float* res0, const float* res1) {
  constexpr int KD  = (MODE == 3 || MODE == 4) ? 512 : 256;
  constexpr int LDA = (MODE == 4) ? 512 : 256;
  constexpr int NKC = KD / 64;

  const int z = blockIdx.z;
  const bf16* Aa = z ? Aa1 : Aa0;
  const bf16* Ac = z ? Ac1 : Ac0;
  bf16*  ob = z ? ob1 : ob0;
  float* of = z ? of1 : of0;
  const float* res = z ? res1 : res0;

  const int tid = threadIdx.x;
  const int lane = tid & 63;
  const int w = tid >> 6;
  const int wr = w >> 1, wc = w & 1;
  const int m0r = blockIdx.x * 128;
  const int n0 = blockIdx.y * 64;
  const int r15 = lane & 15, g = lane >> 4, rb = r15 & 7;
  const int l3 = lane >> 3, l7 = lane & 7;
  const int swzc = (l7 ^ l3) * 8;

  __shared__ bf16 At[2][8192];    // [buf][128 rows x 64 cols], XOR-swizzled
  __shared__ bf16 Bt[2][4096];    // [buf][ 64 rows x 64 cols], XOR-swizzled

  const bf16* aA = Aa + (size_t)(m0r + w*32 + l3) * LDA + swzc;
  const bf16* aC = (MODE == 3) ? (Ac + (size_t)(m0r + w*32 + l3) * 256 + swzc) : nullptr;
  const bf16* bB = Wt + (size_t)(n0 + w*16 + l3) * KD + swzc;
  const int adst = (w*32) * 64;   // wave-uniform LDS element offsets
  const int bdst = (w*16) * 64;

  auto stage = [&](int buf, int kc) {
    const bf16* ab; int kcol;
    if constexpr (MODE == 3) {
      if (kc < 4) { ab = aA; kcol = kc * 64; } else { ab = aC; kcol = (kc - 4) * 64; }
    } else { ab = aA; kcol = kc * 64; }
#pragma unroll
    for (int i = 0; i < 4; i++)
      lds16(ab + kcol + (size_t)i * 8 * LDA, &At[buf][adst + i*512]);
#pragma unroll
    for (int i = 0; i < 2; i++)
      lds16(bB + kc*64 + (size_t)i * 8 * KD, &Bt[buf][bdst + i*512]);
  };

  f32x4 acc[4][2];
#pragma unroll
  for (int i = 0; i < 4; i++)
#pragma unroll
    for (int j = 0; j < 2; j++) acc[i][j] = f32x4{0.f, 0.f, 0.f, 0.f};

  const int rx0 = ((0*4 + g) ^ rb) << 4;
  const int rx1 = ((1*4 + g) ^ rb) << 4;

  auto compute = [&](int cur) {
    const char* Ap = (const char*)&At[cur][0];
    const char* Bp = (const char*)&Bt[cur][0];
    __builtin_amdgcn_s_setprio(1);
#pragma unroll
    for (int ks = 0; ks < 2; ++ks) {
      const int rx = ks ? rx1 : rx0;
      bf16x8 af[4], bfr[2];
#pragma unroll
      for (int mf = 0; mf < 4; ++mf)
        af[mf] = *reinterpret_cast<const bf16x8*>(Ap + (wr*64 + mf*16 + r15) * 128 + rx);
#pragma unroll
      for (int nf = 0; nf < 2; ++nf)
        bfr[nf] = *reinterpret_cast<const bf16x8*>(Bp + (wc*32 + nf*16 + r15) * 128 + rx);
#pragma unroll
      for (int mf = 0; mf < 4; ++mf)
#pragma unroll
        for (int nf = 0; nf < 2; ++nf)
          acc[mf][nf] = MFMA(af[mf], bfr[nf], acc[mf][nf]);
    }
    __builtin_amdgcn_s_setprio(0);
  };

  stage(0, 0);
  int cur = 0;
  for (int kc = 0; kc < NKC - 1; ++kc) {
    stage(cur ^ 1, kc + 1);
    asm volatile("s_waitcnt vmcnt(6)" ::: "memory");
    __builtin_amdgcn_sched_barrier(0);
    __builtin_amdgcn_s_barrier();
    __builtin_amdgcn_sched_barrier(0);
    compute(cur);
    asm volatile("s_waitcnt lgkmcnt(0)" ::: "memory");
    __builtin_amdgcn_sched_barrier(0);
    __builtin_amdgcn_s_barrier();
    __builtin_amdgcn_sched_barrier(0);
    cur ^= 1;
  }
  asm volatile("s_waitcnt vmcnt(0)" ::: "memory");
  __builtin_amdgcn_sched_barrier(0);
  __builtin_amdgcn_s_barrier();
  __builtin_amdgcn_sched_barrier(0);
  compute(cur);

  // ---- epilogue ----
#pragma unroll
  for (int mf = 0; mf < 4; ++mf)
#pragma unroll
    for (int nf = 0; nf < 2; ++nf) {
      f32x4 c = acc[mf][nf];
      int cg = n0 + wc*32 + nf*16 + r15;
#pragma unroll
      for (int r = 0; r < 4; ++r) {
        int rg = m0r + wr*64 + mf*16 + g*4 + r;
        if constexpr (MODE == 5) {
          int b = rg >> 11, n = rg & 2047;
          if (cg < 256) {
            float val = (c[r] + bias[cg]) * SS2;
            int h = cg >> 6, dh = cg & 63;
            ob[(((size_t)(b*Hh + h)) * Nn + n) * 64 + dh] = (bf16)val;
          } else {
            int cg2 = cg - 256;
            float val = c[r] + res[cg2];           // res carries bv
            int h = cg2 >> 6, dh = cg2 & 63;
            ((bf16*)of)[(((size_t)(b*Hh + h)) * 64 + dh) * Nn + n] = (bf16)val;
          }
        } else {
          float val = c[r] + bias[cg];
          if constexpr (MODE == 2) {
            ob[(size_t)rg * 256 + cg] = (bf16)val;
          } else if constexpr (MODE == 3) {
            ob[(size_t)rg * 512 + cg] = (bf16)val;
          } else {
            of[(size_t)rg * 256 + cg] = val + (float)Ac[(size_t)rg * 256 + cg];
          }
        }
      }
    }
}

// ---------------- fused dual-direction attention, 32x32 MFMA, in-register P ----------------
// 128 i-rows/block (4 waves x 32), j-tile 64. K/V double-buffered via
// global_load_lds + counted vmcnt + raw barriers, XOR-swizzled LDS.
// S^T = mfma32(K,Q); P formed IN REGISTERS via exp2 + bf16x2 pack +
// v_permlane32_swap_b32 (no E LDS round-trip); rowsum via mfma32(P, ones)
// whose D-rows align with the O accumulator rows.
__global__ __launch_bounds__(256, 2) void attn_k(
    const bf16* qks0, const bf16* qks1, const bf16* vT0, const bf16* vT1,
    bf16* m0o, bf16* m1o) {
  const int B = blockIdx.x + 16 * (blockIdx.y + 16 * blockIdx.z);
  const int xcd = B & 7, kk = B >> 3;          // kk 0..63
  const int group = 4 * xcd + (kk >> 4);       // 0..31 = dir*16 + bh
  const int it = kk & 15;
  const int bh = group & 15, dir = group >> 4;

  const bf16* Q  = (dir ? qks1 : qks0) + (size_t)bh * (Nn * 64);
  const bf16* Kp = (dir ? qks0 : qks1) + (size_t)bh * (Nn * 64);
  const bf16* Vp = (dir ? vT0  : vT1 ) + (size_t)bh * (64 * Nn);
  bf16* out = dir ? m1o : m0o;
  const int b = bh >> 2, h = bh & 3;

  const int tid = threadIdx.x, lane = tid & 63, w = tid >> 6;
  const int l31 = lane & 31, hi = lane >> 5, xr = l31 & 7;
  const int iw = it * 128 + w * 32;            // wave's first q-row

  __shared__ bf16 Kt[2][4096];                 // [buf][64 j x 64 d], swizzled
  __shared__ bf16 Vt[2][4096];                 // [buf][64 d x 64 j], swizzled

  // ---- Q fragments (B-operand: col i = l31, k d = kt*16 + hi*8 + e) ----
  bf16x8 qf[4];
#pragma unroll
  for (int kt = 0; kt < 4; ++kt)
    qf[kt] = *reinterpret_cast<const bf16x8*>(
        &Q[(size_t)(iw + l31) * 64 + kt*16 + hi*8]);

  bf16x8 ones;
#pragma unroll
  for (int i = 0; i < 8; ++i) ones[i] = (bf16)1.0f;

  f32x16 acc[2]; acc[0] = zero16(); acc[1] = zero16();
  f32x16 rsacc = zero16();

  // ---- staging (pre-swizzled global sources, linear LDS dests) ----
  const int l3 = lane >> 3, l7 = lane & 7;
  const int swz = ((l7 ^ l3) * 8);
  const bf16* ks0 = Kp + (size_t)(w*16 +     l3) * 64 + swz;
  const bf16* ks1 = Kp + (size_t)(w*16 + 8 + l3) * 64 + swz;
  const bf16* vs0 = Vp + (size_t)(w*16 +     l3) * 2048 + swz;
  const bf16* vs1 = Vp + (size_t)(w*16 + 8 + l3) * 2048 + swz;
  const int kd0 = (w*16    ) * 64;
  const int kd1 = (w*16 + 8) * 64;

  auto stage = [&](int buf, int j0) {
    lds16(ks0 + (size_t)j0 * 64, &Kt[buf][kd0]);
    lds16(ks1 + (size_t)j0 * 64, &Kt[buf][kd1]);
    lds16(vs0 + j0,              &Vt[buf][kd0]);
    lds16(vs1 + j0,              &Vt[buf][kd1]);
  };

  // read-offset tables (bytes)
  int kby[2][4], vby[2][4];
#pragma unroll
  for (int jm = 0; jm < 2; ++jm)
#pragma unroll
    for (int kt = 0; kt < 4; ++kt)
      kby[jm][kt] = (jm*32 + l31) * 128 + (((2*kt + hi) ^ xr) << 4);
#pragma unroll
  for (int nt = 0; nt < 2; ++nt)
#pragma unroll
    for (int gg = 0; gg < 4; ++gg)
      vby[nt][gg] = (nt*32 + l31) * 128 + (((2*gg + hi) ^ xr) << 4);

  auto compute_tile = [&](int cur) {
    const char* Kb = (const char*)&Kt[cur][0];
    const char* Vb = (const char*)&Vt[cur][0];
    // --- QK^T: S^T[j][i], D-layout rows j = (r&3)+8*(r>>2)+4*hi (+32*jm), col i = l31 ---
    f32x16 st[2];
    __builtin_amdgcn_s_setprio(1);
#pragma unroll
    for (int jm = 0; jm < 2; ++jm) {
      f32x16 t = zero16();
#pragma unroll
      for (int kt = 0; kt < 4; ++kt) {
        bf16x8 kf = *reinterpret_cast<const bf16x8*>(Kb + kby[jm][kt]);
        t = MFMA32(kf, qf[kt], t);
      }
      st[jm] = t;
    }
    __builtin_amdgcn_s_setprio(0);
    // --- exp2 + bf16x2 pack + permlane32_swap -> PA fragments (in-register) ---
    // dw[jm][s]: s = 2q+h, contains j = 8q + 4hi + 2h + {0,1} (+32*jm)
    bf16x8 pa[4];
#pragma unroll
    for (int jm = 0; jm < 2; ++jm) {
      unsigned dw[8];
#pragma unroll
      for (int s = 0; s < 8; ++s) {
        float e0 = __builtin_amdgcn_exp2f(st[jm][2*s]);
        float e1 = __builtin_amdgcn_exp2f(st[jm][2*s + 1]);
        bf16x2 p; p[0] = (bf16)e0; p[1] = (bf16)e1;
        dw[s] = __builtin_bit_cast(unsigned, p);
      }
#pragma unroll
      for (int kt2 = 0; kt2 < 2; ++kt2) {
        unsigned a0 = dw[4*kt2 + 0], b0 = dw[4*kt2 + 2];
        unsigned a1 = dw[4*kt2 + 1], b1 = dw[4*kt2 + 3];
        // a' = [a.lo | b.lo], b' = [a.hi | b.hi]
        asm volatile("v_permlane32_swap_b32 %0, %1" : "+v"(a0), "+v"(b0));
        asm volatile("v_permlane32_swap_b32 %0, %1" : "+v"(a1), "+v"(b1));
        u32x4 uu; uu[0] = a0; uu[1] = a1; uu[2] = b0; uu[3] = b1;
        pa[jm*2 + kt2] = __builtin_bit_cast(bf16x8, uu);
      }
    }
    // --- PV + rowsum (A = PA, rows i = l31; k = j 16 per tile) ---
    __builtin_amdgcn_s_setprio(1);
#pragma unroll
    for (int gg = 0; gg < 4; ++gg) {
      rsacc = MFMA32(pa[gg], ones, rsacc);
#pragma unroll
      for (int nt = 0; nt < 2; ++nt) {
        bf16x8 vf = *reinterpret_cast<const bf16x8*>(Vb + vby[nt][gg]);
        acc[nt] = MFMA32(pa[gg], vf, acc[nt]);
      }
    }
    __builtin_amdgcn_s_setprio(0);
  };

  // ---- pipelined main loop: 32 j-tiles, last one peeled ----
  stage(0, 0);
  int cur = 0;
  for (int jt = 0; jt < 31; ++jt) {
    stage(cur ^ 1, (jt + 1) << 6);
    asm volatile("s_waitcnt vmcnt(4)" ::: "memory");
    __builtin_amdgcn_sched_barrier(0);
    __builtin_amdgcn_s_barrier();
    __builtin_amdgcn_sched_barrier(0);
    compute_tile(cur);
    asm volatile("s_waitcnt lgkmcnt(0)" ::: "memory");
    __builtin_amdgcn_sched_barrier(0);
    __builtin_amdgcn_s_barrier();
    __builtin_amdgcn_sched_barrier(0);
    cur ^= 1;
  }
  asm volatile("s_waitcnt vmcnt(0)" ::: "memory");
  __builtin_amdgcn_sched_barrier(0);
  __builtin_amdgcn_s_barrier();
  __builtin_amdgcn_sched_barrier(0);
  compute_tile(cur);

  // ---- epilogue: divide by rowsum (row-aligned regs), write out ----
#pragma unroll
  for (int r = 0; r < 16; ++r) {
    float inv = 1.0f / rsacc[r];
    int row = iw + (r & 3) + 8*(r >> 2) + 4*hi;
#pragma unroll
    for (int nt = 0; nt < 2; ++nt) {
      int col = h*64 + nt*32 + l31;
      out[((size_t)b * Nn + row) * 256 + col] = (bf16)(acc[nt][r] * inv);
    }
  }
}

// ---------------- LayerNorm + exact GELU, in-place on bf16 h ----------------
__global__ __launch_bounds__(256) void ln_gelu_k(
    bf16* hg, const float* g, const float* bb) {
  const size_t row = blockIdx.x;
  const int tid = threadIdx.x;
  bf16* hr = hg + row * 512;
  bf16x2 v2 = *reinterpret_cast<const bf16x2*>(&hr[tid * 2]);
  float vx = (float)v2[0], vy = (float)v2[1];
  float s = vx + vy;
  float sq = vx * vx + vy * vy;
#pragma unroll
  for (int m = 1; m < 64; m <<= 1) {
    s += __shfl_xor(s, m);
    sq += __shfl_xor(sq, m);
  }
  __shared__ float ws_s[4], ws_q[4];
  int w = tid >> 6, lane = tid & 63;
  if (lane == 0) { ws_s[w] = s; ws_q[w] = sq; }
  __syncthreads();
  s = ws_s[0] + ws_s[1] + ws_s[2] + ws_s[3];
  sq = ws_q[0] + ws_q[1] + ws_q[2] + ws_q[3];
  float mu = s * (1.f / 512.f);
  float var = sq * (1.f / 512.f) - mu * mu;
  float rsv = rsqrtf(var + 1e-5f);
  bf16x2 o2;
#pragma unroll
  for (int i = 0; i < 2; i++) {
    int c = tid * 2 + i;
    float xv = i ? vy : vx;
    float xn = (xv - mu) * rsv * g[c] + bb[c];
    float ge = 0.5f * xn * (1.f + erff(xn * 0.70710678118f));
    o2[i] = (bf16)ge;
  }
  *reinterpret_cast<bf16x2*>(&hr[tid * 2]) = o2;
}

extern "C" void kernel_launch(void* const* d_in, const int* in_sizes, int n_in,
                              void* d_out, int out_size, void* d_ws, size_t ws_size,
                              hipStream_t stream) {
  (void)in_sizes; (void)n_in; (void)out_size; (void)ws_size;
  const float* x0   = (const float*)d_in[0];
  const float* x1   = (const float*)d_in[1];
  const float* Wqk  = (const float*)d_in[2];
  const float* bqk  = (const float*)d_in[3];
  const float* Wv   = (const float*)d_in[4];
  const float* bv   = (const float*)d_in[5];
  const float* Wout = (const float*)d_in[6];
  const float* bout = (const float*)d_in[7];
  const float* Wf1  = (const float*)d_in[8];
  const float* bf1  = (const float*)d_in[9];
  const float* ln_g = (const float*)d_in[10];
  const float* ln_b = (const float*)d_in[11];
  const float* Wf2  = (const float*)d_in[12];
  const float* bf2  = (const float*)d_in[13];
  float* y = (float*)d_out;

  bf16* p = (bf16*)d_ws;
  bf16* wqkv_t = p; p += 131072;
  bf16* wout_t = p; p += 65536;
  bf16* wf1_t  = p; p += 262144;
  bf16* wf2_t  = p; p += 131072;
  bf16* xb0  = p; p += 2097152;
  bf16* xb1  = p; p += 2097152;
  bf16* qks0 = p; p += 2097152;
  bf16* qks1 = p; p += 2097152;
  bf16* vT0  = p; p += 2097152;
  bf16* vT1  = p; p += 2097152;
  bf16* m0   = p; p += 2097152;
  bf16* m1   = p; p += 2097152;
  bf16* mo0  = p; p += 2097152;
  bf16* mo1  = p; p += 2097152;
  bf16* hg0  = p; p += 4194304;
  bf16* hg1  = p; p += 4194304;

  dim3 blk(256);
  prep_k<<<6400, blk, 0, stream>>>(Wqk, Wv, Wout, Wf1, Wf2, x0, x1,
                                   wqkv_t, wout_t, wf1_t, wf2_t, xb0, xb1);
  gemm_k<5><<<dim3(64, 8, 2), blk, 0, stream>>>(xb0, xb1, nullptr, nullptr, wqkv_t, bqk,
                                                qks0, qks1, (float*)vT0, (float*)vT1, bv, bv);
  attn_k<<<dim3(16, 16, 2), blk, 0, stream>>>(qks0, qks1, vT0, vT1, m0, m1);
  gemm_k<2><<<dim3(64, 4, 2), blk, 0, stream>>>(m0, m1, nullptr, nullptr, wout_t, bout,
                                                mo0, mo1, nullptr, nullptr, nullptr, nullptr);
  gemm_k<3><<<dim3(64, 8, 2), blk, 0, stream>>>(xb0, xb1, mo0, mo1, wf1_t, bf1,
                                                hg0, hg1, nullptr, nullptr, nullptr, nullptr);
  ln_gelu_k<<<dim3(16384), blk, 0, stream>>>(hg0, ln_g, ln_b);
  gemm_k<4><<<dim3(64, 4, 2), blk, 0, stream>>>(hg0, hg1, xb0, xb1, wf2_t, bf2,
                                                nullptr, nullptr, y, y + 2097152, nullptr, nullptr);
}